// Round 2
// baseline (39193.045 us; speedup 1.0000x reference)
//
#include <hip/hip_runtime.h>
#include <math.h>

#define B64 64
#define H 1024
#define DD 8
#define ENC 96
#define HOR 336
#define TT 432
#define NSTEP 431
#define NBLK 256
#define KS0 32      // K=1024 in 32-wide chunks
#define KS1 64      // K=2048

typedef __attribute__((ext_vector_type(8))) short short8;
typedef __attribute__((ext_vector_type(4))) float f32x4;

__device__ __forceinline__ unsigned short f2bf(float x) {
    union { float f; unsigned u; } v; v.f = x;
    unsigned r = v.u + 0x7fffu + ((v.u >> 16) & 1u);
    return (unsigned short)(r >> 16);
}
__device__ __forceinline__ float sigm(float x) { return 1.0f / (1.0f + __expf(-x)); }

// ---------------- prep kernels (verified in round 0) ----------------

__global__ void zero_k(unsigned int* __restrict__ p, int n) {
    for (int i = blockIdx.x * 256 + threadIdx.x; i < n; i += gridDim.x * 256) p[i] = 0u;
}

// pack whh0 (4096x1024) -> Wp0 [nb:128][nt:2][ks:32][lane:64][j:8] bf16
__global__ void pack0_k(const float* __restrict__ w, unsigned short* __restrict__ dst) {
    const int total = 128 * 2 * KS0 * 64 * 8;
    for (int idx = blockIdx.x * 256 + threadIdx.x; idx < total; idx += gridDim.x * 256) {
        int j = idx & 7, lane = (idx >> 3) & 63, ks = (idx >> 9) & 31, nt = (idx >> 14) & 1, nb = idx >> 15;
        int rr = nt * 16 + (lane & 15);
        int row = nb * 8 + (rr >> 2) + 1024 * (rr & 3);
        int k = ks * 32 + ((lane >> 4) << 3) + j;
        dst[idx] = f2bf(w[row * 1024 + k]);
    }
}

// pack [wih1 | whh1] (4096 x 2048) -> Wp1 [nb:128][nt:2][ks:64][lane:64][j:8]
__global__ void pack1_k(const float* __restrict__ wih, const float* __restrict__ whh,
                        unsigned short* __restrict__ dst) {
    const int total = 128 * 2 * KS1 * 64 * 8;
    for (int idx = blockIdx.x * 256 + threadIdx.x; idx < total; idx += gridDim.x * 256) {
        int j = idx & 7, lane = (idx >> 3) & 63, ks = (idx >> 9) & 63, nt = (idx >> 15) & 1, nb = idx >> 16;
        int rr = nt * 16 + (lane & 15);
        int row = nb * 8 + (rr >> 2) + 1024 * (rr & 3);
        int k = ks * 32 + ((lane >> 4) << 3) + j;
        float v = (k < 1024) ? wih[row * 1024 + k] : whh[row * 1024 + (k - 1024)];
        dst[idx] = f2bf(v);
    }
}

// pack wih2 (32 x 1024) -> Wp2 [nt:2][ks:32][lane:64][j:8]
__global__ void pack2_k(const float* __restrict__ w, unsigned short* __restrict__ dst) {
    const int total = 2 * KS0 * 64 * 8;
    for (int idx = blockIdx.x * 256 + threadIdx.x; idx < total; idx += gridDim.x * 256) {
        int j = idx & 7, lane = (idx >> 3) & 63, ks = (idx >> 9) & 31, nt = (idx >> 14) & 1;
        int rr = nt * 16 + (lane & 15);
        int row = (rr >> 2) + 8 * (rr & 3);
        int k = ks * 32 + ((lane >> 4) << 3) + j;
        dst[idx] = f2bf(w[row * 1024 + k]);
    }
}

__global__ void copy_y_k(const float* __restrict__ inp, float* __restrict__ y) {
    const int total = B64 * HOR * DD;
    for (int i = blockIdx.x * 256 + threadIdx.x; i < total; i += gridDim.x * 256) {
        int b = i / (HOR * DD);
        int rem = i - b * (HOR * DD);
        y[i] = inp[b * (TT * DD) + ENC * DD + rem];
    }
}

__global__ void loss_k(const float* __restrict__ pred, const float* __restrict__ y,
                       float* __restrict__ loss) {
    __shared__ float part[256];
    int tid = threadIdx.x;
    int dd = tid & 7, cc = tid >> 3;
    float s = 0.f;
    for (int i = cc; i < B64 * HOR; i += 32) {
        float d = pred[i * 8 + dd] - y[i * 8 + dd];
        s += d * d;
    }
    part[tid] = s;
    __syncthreads();
    if (tid < 8) {
        float t = 0.f;
        for (int r = 0; r < 32; ++r) t += part[r * 8 + tid];
        loss[tid] = t / (float)(B64 * HOR);
    }
}

// ---------------- grid barrier (two-level, monotonic epochs) ----------------
// bar[64*g] g<8 : group counters (256B apart); bar[512]: root; bar[520]: release
__device__ __forceinline__ void gbar(unsigned* bar, unsigned ep) {
    __syncthreads();
    __threadfence();                       // release: drain + L2 writeback
    if (threadIdx.x == 0) {
        unsigned g = blockIdx.x & 7;
        unsigned v = __hip_atomic_fetch_add(&bar[64 * g], 1u, __ATOMIC_RELAXED,
                                            __HIP_MEMORY_SCOPE_AGENT) + 1u;
        if (v == 32u * ep) {
            unsigned r = __hip_atomic_fetch_add(&bar[512], 1u, __ATOMIC_RELAXED,
                                                __HIP_MEMORY_SCOPE_AGENT) + 1u;
            if (r == 8u * ep)
                __hip_atomic_store(&bar[520], ep, __ATOMIC_RELEASE, __HIP_MEMORY_SCOPE_AGENT);
        }
        while (__hip_atomic_load(&bar[520], __ATOMIC_ACQUIRE, __HIP_MEMORY_SCOPE_AGENT) < ep)
            __builtin_amdgcn_s_sleep(2);
    }
    __syncthreads();
    __threadfence();                       // acquire: invalidate L1/L2
}

// ---------------- persistent recurrence kernel ----------------
// 256 blocks x 256 thr, 1 block/CU (grid == CU count -> all co-resident).
// block = (bg = batch half, rb = 8 hidden units); weights live in VGPRs.
__global__ __launch_bounds__(256, 1) void persist_k(
    const unsigned short* __restrict__ Wp0,
    const unsigned short* __restrict__ Wp1,
    const unsigned short* __restrict__ Wp2,
    const float* __restrict__ wih0, const float* __restrict__ b0v,
    const float* __restrict__ b1v,
    const float* __restrict__ whh2, const float* __restrict__ b2v,
    const float* __restrict__ inp,
    unsigned short* __restrict__ H0a, unsigned short* __restrict__ H0b,
    unsigned short* __restrict__ H1a, unsigned short* __restrict__ H1b,
    unsigned* __restrict__ bar, float* __restrict__ pred)
{
    const int tid = threadIdx.x;
    const int wv = tid >> 6, lane = tid & 63;
    const int blk = blockIdx.x;
    const int bg = blk & 1, rb = blk >> 1;
    const int bl = tid & 31, u = tid >> 5;
    const int mtl = bl >> 4, m16 = bl & 15;

    __shared__ float red[16 * 272];   // [frag 16][n*17+m] swizzled K-reduce buffer
    __shared__ float h2x[32 * 9];     // h2 (layer-2 hidden) for this block's 32 batches

    for (int i = tid; i < 32 * 9; i += 256) h2x[i] = 0.f;

    // ---- weights -> registers (read exactly once) ----
    short8 Wr0[2][8], Wr1[2][16], Wr2[2][8];
    {
        const short8* p0 = (const short8*)Wp0;
        const short8* p1 = (const short8*)Wp1;
        const short8* p2 = (const short8*)Wp2;
        #pragma unroll
        for (int ot = 0; ot < 2; ++ot) {
            #pragma unroll
            for (int kk = 0; kk < 8; ++kk)
                Wr0[ot][kk] = p0[((rb * 2 + ot) * KS0 + (8 * wv + kk)) * 64 + lane];
            #pragma unroll
            for (int kk = 0; kk < 16; ++kk)
                Wr1[ot][kk] = p1[((rb * 2 + ot) * KS1 + (16 * wv + kk)) * 64 + lane];
            #pragma unroll
            for (int kk = 0; kk < 8; ++kk)
                Wr2[ot][kk] = p2[(ot * KS0 + (8 * wv + kk)) * 64 + lane];
        }
    }
    // ---- per-thread cell constants ----
    float wih0r[4][8], whh2r[4][8], b0r[4], b1r[4], b2r[4];
    #pragma unroll
    for (int g = 0; g < 4; ++g) {
        int row = rb * 8 + u + 1024 * g;
        #pragma unroll
        for (int d = 0; d < 8; ++d) wih0r[g][d] = wih0[row * 8 + d];
        b0r[g] = b0v[row];
        b1r[g] = b1v[row];
        int row2 = u + 8 * g;
        #pragma unroll
        for (int d = 0; d < 8; ++d) whh2r[g][d] = whh2[row2 * 8 + d];
        b2r[g] = b2v[row2];
    }
    float c0r = 0.f, c1r = 0.f, c2r = 0.f;
    unsigned ep = 0;
    __syncthreads();

    for (int t = 0; t < NSTEP; ++t) {
        const int par = t & 1;
        unsigned short* H0w = par ? H0b : H0a;
        const unsigned short* H0r = par ? H0a : H0b;   // h0(t-1)
        unsigned short* H1w = par ? H1b : H1a;
        const unsigned short* H1r = par ? H1a : H1b;   // h1(t-1)

        // ================= P1 : layer 0 =================
        {
            f32x4 acc[2][2];
            #pragma unroll
            for (int m = 0; m < 2; ++m)
                #pragma unroll
                for (int ot = 0; ot < 2; ++ot) acc[m][ot] = (f32x4){0.f, 0.f, 0.f, 0.f};
            const short8* src = (const short8*)H0r;
            #pragma unroll
            for (int kk = 0; kk < 8; ++kk) {
                short8 a0 = src[((bg * 2 + 0) * KS0 + 8 * wv + kk) * 64 + lane];
                short8 a1 = src[((bg * 2 + 1) * KS0 + 8 * wv + kk) * 64 + lane];
                #pragma unroll
                for (int ot = 0; ot < 2; ++ot) {
                    acc[0][ot] = __builtin_amdgcn_mfma_f32_16x16x32_bf16(a0, Wr0[ot][kk], acc[0][ot], 0, 0, 0);
                    acc[1][ot] = __builtin_amdgcn_mfma_f32_16x16x32_bf16(a1, Wr0[ot][kk], acc[1][ot], 0, 0, 0);
                }
            }
            #pragma unroll
            for (int m = 0; m < 2; ++m)
                #pragma unroll
                for (int ot = 0; ot < 2; ++ot) {
                    int base = ((wv * 2 + m) * 2 + ot) * 272 + (lane & 15) * 17 + (lane >> 4) * 4;
                    #pragma unroll
                    for (int r = 0; r < 4; ++r) red[base + r] = acc[m][ot][r];
                }
            __syncthreads();
            float xv[8];
            if (t < ENC) {
                int b = bg * 32 + bl;
                #pragma unroll
                for (int d = 0; d < 8; ++d) xv[d] = inp[(b * TT + t) * DD + d];
            } else {
                #pragma unroll
                for (int d = 0; d < 8; ++d) xv[d] = h2x[bl * 9 + d];
            }
            float g4[4];
            #pragma unroll
            for (int g = 0; g < 4; ++g) {
                int rr = u * 4 + g, ot = rr >> 4, rr16 = rr & 15;
                float s = b0r[g];
                #pragma unroll
                for (int w2 = 0; w2 < 4; ++w2)
                    s += red[((w2 * 2 + mtl) * 2 + ot) * 272 + rr16 * 17 + m16];
                #pragma unroll
                for (int d = 0; d < 8; ++d) s += wih0r[g][d] * xv[d];
                g4[g] = s;
            }
            c0r = sigm(g4[1]) * c0r + sigm(g4[0]) * tanhf(g4[2]);
            float hn = sigm(g4[3]) * tanhf(c0r);
            int b = bg * 32 + bl, k = rb * 8 + u;
            H0w[(((b >> 4) * KS0 + (k >> 5)) * 64 + ((b & 15) | (((k >> 3) & 3) << 4))) * 8 + (k & 7)] = f2bf(hn);
        }
        gbar(bar, ++ep);

        // ================= P2 : layer 1 (K = 2048 = [h0(t) | h1(t-1)]) =================
        {
            f32x4 acc[2][2];
            #pragma unroll
            for (int m = 0; m < 2; ++m)
                #pragma unroll
                for (int ot = 0; ot < 2; ++ot) acc[m][ot] = (f32x4){0.f, 0.f, 0.f, 0.f};
            const short8* src = (wv < 2) ? (const short8*)H0w : (const short8*)H1r;
            const int kb = (wv & 1) * 16;
            #pragma unroll
            for (int kk = 0; kk < 16; ++kk) {
                short8 a0 = src[((bg * 2 + 0) * KS0 + kb + kk) * 64 + lane];
                short8 a1 = src[((bg * 2 + 1) * KS0 + kb + kk) * 64 + lane];
                #pragma unroll
                for (int ot = 0; ot < 2; ++ot) {
                    acc[0][ot] = __builtin_amdgcn_mfma_f32_16x16x32_bf16(a0, Wr1[ot][kk], acc[0][ot], 0, 0, 0);
                    acc[1][ot] = __builtin_amdgcn_mfma_f32_16x16x32_bf16(a1, Wr1[ot][kk], acc[1][ot], 0, 0, 0);
                }
            }
            #pragma unroll
            for (int m = 0; m < 2; ++m)
                #pragma unroll
                for (int ot = 0; ot < 2; ++ot) {
                    int base = ((wv * 2 + m) * 2 + ot) * 272 + (lane & 15) * 17 + (lane >> 4) * 4;
                    #pragma unroll
                    for (int r = 0; r < 4; ++r) red[base + r] = acc[m][ot][r];
                }
            __syncthreads();
            float g4[4];
            #pragma unroll
            for (int g = 0; g < 4; ++g) {
                int rr = u * 4 + g, ot = rr >> 4, rr16 = rr & 15;
                float s = b1r[g];
                #pragma unroll
                for (int w2 = 0; w2 < 4; ++w2)
                    s += red[((w2 * 2 + mtl) * 2 + ot) * 272 + rr16 * 17 + m16];
                g4[g] = s;
            }
            c1r = sigm(g4[1]) * c1r + sigm(g4[0]) * tanhf(g4[2]);
            float hn = sigm(g4[3]) * tanhf(c1r);
            int b = bg * 32 + bl, k = rb * 8 + u;
            H1w[(((b >> 4) * KS0 + (k >> 5)) * 64 + ((b & 15) | (((k >> 3) & 3) << 4))) * 8 + (k & 7)] = f2bf(hn);
        }
        gbar(bar, ++ep);

        // ================= P3 : layer 2 (replicated per block) =================
        {
            f32x4 acc[2][2];
            #pragma unroll
            for (int m = 0; m < 2; ++m)
                #pragma unroll
                for (int ot = 0; ot < 2; ++ot) acc[m][ot] = (f32x4){0.f, 0.f, 0.f, 0.f};
            const short8* src = (const short8*)H1w;
            #pragma unroll
            for (int kk = 0; kk < 8; ++kk) {
                short8 a0 = src[((bg * 2 + 0) * KS0 + 8 * wv + kk) * 64 + lane];
                short8 a1 = src[((bg * 2 + 1) * KS0 + 8 * wv + kk) * 64 + lane];
                #pragma unroll
                for (int ot = 0; ot < 2; ++ot) {
                    acc[0][ot] = __builtin_amdgcn_mfma_f32_16x16x32_bf16(a0, Wr2[ot][kk], acc[0][ot], 0, 0, 0);
                    acc[1][ot] = __builtin_amdgcn_mfma_f32_16x16x32_bf16(a1, Wr2[ot][kk], acc[1][ot], 0, 0, 0);
                }
            }
            #pragma unroll
            for (int m = 0; m < 2; ++m)
                #pragma unroll
                for (int ot = 0; ot < 2; ++ot) {
                    int base = ((wv * 2 + m) * 2 + ot) * 272 + (lane & 15) * 17 + (lane >> 4) * 4;
                    #pragma unroll
                    for (int r = 0; r < 4; ++r) red[base + r] = acc[m][ot][r];
                }
            __syncthreads();
            float xo[8];
            #pragma unroll
            for (int d = 0; d < 8; ++d) xo[d] = h2x[bl * 9 + d];
            float g4[4];
            #pragma unroll
            for (int g = 0; g < 4; ++g) {
                int rr = u * 4 + g, ot = rr >> 4, rr16 = rr & 15;
                float s = b2r[g];
                #pragma unroll
                for (int w2 = 0; w2 < 4; ++w2)
                    s += red[((w2 * 2 + mtl) * 2 + ot) * 272 + rr16 * 17 + m16];
                #pragma unroll
                for (int d = 0; d < 8; ++d) s += whh2r[g][d] * xo[d];
                g4[g] = s;
            }
            float cn = sigm(g4[1]) * c2r + sigm(g4[0]) * tanhf(g4[2]);
            c2r = cn;
            float hn = sigm(g4[3]) * tanhf(cn);
            __syncthreads();           // all old-h2x reads done before overwrite
            h2x[bl * 9 + u] = hn;
            if (rb == 0 && t >= ENC - 1)
                pred[((bg * 32 + bl) * HOR + (t - (ENC - 1))) * DD + u] = hn;
        }
        // no barrier needed here: next P1 touches only H0 buffers + local LDS
    }
}

// ---------------- host ----------------

extern "C" void kernel_launch(void* const* d_in, const int* in_sizes, int n_in,
                              void* d_out, int out_size, void* d_ws, size_t ws_size,
                              hipStream_t stream)
{
    const float* inp  = (const float*)d_in[0];
    const float* wih0 = (const float*)d_in[1];
    const float* whh0 = (const float*)d_in[2];
    const float* b0v  = (const float*)d_in[3];
    const float* wih1 = (const float*)d_in[4];
    const float* whh1 = (const float*)d_in[5];
    const float* b1v  = (const float*)d_in[6];
    const float* wih2 = (const float*)d_in[7];
    const float* whh2 = (const float*)d_in[8];
    const float* b2v  = (const float*)d_in[9];
    float* out = (float*)d_out;   // pred[172032] | y[172032] | loss[8]

    char* base = (char*)d_ws;
    size_t off = 0;
    auto carve = [&](size_t bytes) -> void* {
        void* p = base + off;
        off += (bytes + 255) & ~((size_t)255);
        return p;
    };
    unsigned short* Wp0 = (unsigned short*)carve((size_t)128 * 2 * KS0 * 64 * 8 * 2);
    unsigned short* Wp1 = (unsigned short*)carve((size_t)128 * 2 * KS1 * 64 * 8 * 2);
    unsigned short* Wp2 = (unsigned short*)carve((size_t)2 * KS0 * 64 * 8 * 2);
    size_t state_off = off;
    unsigned short* H0a = (unsigned short*)carve(B64 * H * 2);
    unsigned short* H0b = (unsigned short*)carve(B64 * H * 2);
    unsigned short* H1a = (unsigned short*)carve(B64 * H * 2);
    unsigned short* H1b = (unsigned short*)carve(B64 * H * 2);
    unsigned* bar = (unsigned*)carve(4096);
    size_t state_bytes = off - state_off;
    if (off > ws_size) return;

    zero_k<<<64, 256, 0, stream>>>((unsigned int*)(base + state_off), (int)(state_bytes / 4));
    pack0_k<<<2048, 256, 0, stream>>>(whh0, Wp0);
    pack1_k<<<4096, 256, 0, stream>>>(wih1, whh1, Wp1);
    pack2_k<<<32, 256, 0, stream>>>(wih2, Wp2);
    copy_y_k<<<672, 256, 0, stream>>>(inp, out + 172032);

    persist_k<<<NBLK, 256, 0, stream>>>(Wp0, Wp1, Wp2, wih0, b0v, b1v, whh2, b2v,
                                        inp, H0a, H0b, H1a, H1b, bar, out);

    loss_k<<<1, 256, 0, stream>>>(out, out + 172032, out + 344064);
}

// Round 3
// 13109.396 us; speedup vs baseline: 2.9897x; 2.9897x over previous
//
#include <hip/hip_runtime.h>
#include <math.h>

#define B64 64
#define H 1024
#define DD 8
#define ENC 96
#define HOR 336
#define TT 432
#define NSTEP 431
#define NBLK 256
#define KS0 32      // K=1024 in 32-wide chunks
#define KS1 64      // K=2048

typedef __attribute__((ext_vector_type(8))) short short8;
typedef __attribute__((ext_vector_type(4))) float f32x4;

__device__ __forceinline__ unsigned short f2bf(float x) {
    union { float f; unsigned u; } v; v.f = x;
    unsigned r = v.u + 0x7fffu + ((v.u >> 16) & 1u);
    return (unsigned short)(r >> 16);
}
__device__ __forceinline__ float sigm(float x) { return 1.0f / (1.0f + __expf(-x)); }

// ---------------- prep kernels (verified) ----------------

__global__ void zero_k(unsigned int* __restrict__ p, int n) {
    for (int i = blockIdx.x * 256 + threadIdx.x; i < n; i += gridDim.x * 256) p[i] = 0u;
}

__global__ void pack0_k(const float* __restrict__ w, unsigned short* __restrict__ dst) {
    const int total = 128 * 2 * KS0 * 64 * 8;
    for (int idx = blockIdx.x * 256 + threadIdx.x; idx < total; idx += gridDim.x * 256) {
        int j = idx & 7, lane = (idx >> 3) & 63, ks = (idx >> 9) & 31, nt = (idx >> 14) & 1, nb = idx >> 15;
        int rr = nt * 16 + (lane & 15);
        int row = nb * 8 + (rr >> 2) + 1024 * (rr & 3);
        int k = ks * 32 + ((lane >> 4) << 3) + j;
        dst[idx] = f2bf(w[row * 1024 + k]);
    }
}

__global__ void pack1_k(const float* __restrict__ wih, const float* __restrict__ whh,
                        unsigned short* __restrict__ dst) {
    const int total = 128 * 2 * KS1 * 64 * 8;
    for (int idx = blockIdx.x * 256 + threadIdx.x; idx < total; idx += gridDim.x * 256) {
        int j = idx & 7, lane = (idx >> 3) & 63, ks = (idx >> 9) & 63, nt = (idx >> 15) & 1, nb = idx >> 16;
        int rr = nt * 16 + (lane & 15);
        int row = nb * 8 + (rr >> 2) + 1024 * (rr & 3);
        int k = ks * 32 + ((lane >> 4) << 3) + j;
        float v = (k < 1024) ? wih[row * 1024 + k] : whh[row * 1024 + (k - 1024)];
        dst[idx] = f2bf(v);
    }
}

__global__ void pack2_k(const float* __restrict__ w, unsigned short* __restrict__ dst) {
    const int total = 2 * KS0 * 64 * 8;
    for (int idx = blockIdx.x * 256 + threadIdx.x; idx < total; idx += gridDim.x * 256) {
        int j = idx & 7, lane = (idx >> 3) & 63, ks = (idx >> 9) & 31, nt = (idx >> 14) & 1;
        int rr = nt * 16 + (lane & 15);
        int row = (rr >> 2) + 8 * (rr & 3);
        int k = ks * 32 + ((lane >> 4) << 3) + j;
        dst[idx] = f2bf(w[row * 1024 + k]);
    }
}

__global__ void copy_y_k(const float* __restrict__ inp, float* __restrict__ y) {
    const int total = B64 * HOR * DD;
    for (int i = blockIdx.x * 256 + threadIdx.x; i < total; i += gridDim.x * 256) {
        int b = i / (HOR * DD);
        int rem = i - b * (HOR * DD);
        y[i] = inp[b * (TT * DD) + ENC * DD + rem];
    }
}

__global__ void loss_k(const float* __restrict__ pred, const float* __restrict__ y,
                       float* __restrict__ loss) {
    __shared__ float part[256];
    int tid = threadIdx.x;
    int dd = tid & 7, cc = tid >> 3;
    float s = 0.f;
    for (int i = cc; i < B64 * HOR; i += 32) {
        float d = pred[i * 8 + dd] - y[i * 8 + dd];
        s += d * d;
    }
    part[tid] = s;
    __syncthreads();
    if (tid < 8) {
        float t = 0.f;
        for (int r = 0; r < 32; ++r) t += part[r * 8 + tid];
        loss[tid] = t / (float)(B64 * HOR);
    }
}

// ---------------- grid barrier: RELAXED spin, one fence pair per block ----------------
// Per-domain layout (uints): bar[64*g] g<8 group counters, bar[512] root,
// bar[520] release word. 128 blocks/domain = 8 groups x 16.
__device__ __forceinline__ void gbar(unsigned* bar, unsigned ep, unsigned grp) {
    __syncthreads();                       // all waves' stores drained (vmcnt0 before s_barrier)
    if (threadIdx.x == 0) {
        __builtin_amdgcn_fence(__ATOMIC_RELEASE, "agent");   // wbl2 once per block
        unsigned v = __hip_atomic_fetch_add(&bar[64 * grp], 1u, __ATOMIC_RELAXED,
                                            __HIP_MEMORY_SCOPE_AGENT) + 1u;
        if (v == 16u * ep) {
            unsigned r = __hip_atomic_fetch_add(&bar[512], 1u, __ATOMIC_RELAXED,
                                                __HIP_MEMORY_SCOPE_AGENT) + 1u;
            if (r == 8u * ep) {
                __builtin_amdgcn_fence(__ATOMIC_ACQUIRE, "agent");  // transitivity of release chain
                __hip_atomic_store(&bar[520], ep, __ATOMIC_RELEASE, __HIP_MEMORY_SCOPE_AGENT);
            }
        }
        // RELAXED spin: no per-iteration cache ops (the round-2 killer)
        while (__hip_atomic_load(&bar[520], __ATOMIC_RELAXED, __HIP_MEMORY_SCOPE_AGENT) < ep)
            __builtin_amdgcn_s_sleep(2);
        __builtin_amdgcn_fence(__ATOMIC_ACQUIRE, "agent");   // one inv per block
    }
    __syncthreads();
}

// ---------------- persistent recurrence kernel ----------------
__global__ __launch_bounds__(256, 1) void persist_k(
    const unsigned short* __restrict__ Wp0,
    const unsigned short* __restrict__ Wp1,
    const unsigned short* __restrict__ Wp2,
    const float* __restrict__ wih0, const float* __restrict__ b0v,
    const float* __restrict__ b1v,
    const float* __restrict__ whh2, const float* __restrict__ b2v,
    const float* __restrict__ inp,
    unsigned short* __restrict__ H0a, unsigned short* __restrict__ H0b,
    unsigned short* __restrict__ H1a, unsigned short* __restrict__ H1b,
    unsigned* __restrict__ bar0, float* __restrict__ pred)
{
    const int tid = threadIdx.x;
    const int wv = tid >> 6, lane = tid & 63;
    const int blk = blockIdx.x;
    const int bg = blk & 1, rb = blk >> 1;
    const int bl = tid & 31, u = tid >> 5;
    const int mtl = bl >> 4, m16 = bl & 15;
    unsigned* bar = bar0 + (bg << 10);       // independent barrier domain per batch-half
    const unsigned grp = (unsigned)(rb & 7); // 8 groups x 16 blocks within domain

    __shared__ float red[16 * 272];
    __shared__ float h2x[32 * 9];

    for (int i = tid; i < 32 * 9; i += 256) h2x[i] = 0.f;

    // ---- weights -> registers (read exactly once) ----
    short8 Wr0[2][8], Wr1[2][16], Wr2[2][8];
    {
        const short8* p0 = (const short8*)Wp0;
        const short8* p1 = (const short8*)Wp1;
        const short8* p2 = (const short8*)Wp2;
        #pragma unroll
        for (int ot = 0; ot < 2; ++ot) {
            #pragma unroll
            for (int kk = 0; kk < 8; ++kk)
                Wr0[ot][kk] = p0[((rb * 2 + ot) * KS0 + (8 * wv + kk)) * 64 + lane];
            #pragma unroll
            for (int kk = 0; kk < 16; ++kk)
                Wr1[ot][kk] = p1[((rb * 2 + ot) * KS1 + (16 * wv + kk)) * 64 + lane];
            #pragma unroll
            for (int kk = 0; kk < 8; ++kk)
                Wr2[ot][kk] = p2[(ot * KS0 + (8 * wv + kk)) * 64 + lane];
        }
    }
    float wih0r[4][8], whh2r[4][8], b0r[4], b1r[4], b2r[4];
    #pragma unroll
    for (int g = 0; g < 4; ++g) {
        int row = rb * 8 + u + 1024 * g;
        #pragma unroll
        for (int d = 0; d < 8; ++d) wih0r[g][d] = wih0[row * 8 + d];
        b0r[g] = b0v[row];
        b1r[g] = b1v[row];
        int row2 = u + 8 * g;
        #pragma unroll
        for (int d = 0; d < 8; ++d) whh2r[g][d] = whh2[row2 * 8 + d];
        b2r[g] = b2v[row2];
    }
    float c0r = 0.f, c1r = 0.f, c2r = 0.f;
    unsigned ep = 0;
    __syncthreads();

    for (int t = 0; t < NSTEP; ++t) {
        const int par = t & 1;
        unsigned short* H0w = par ? H0b : H0a;
        const unsigned short* H0r = par ? H0a : H0b;
        unsigned short* H1w = par ? H1b : H1a;
        const unsigned short* H1r = par ? H1a : H1b;

        // ================= P1 : layer 0 =================
        {
            f32x4 acc[2][2];
            #pragma unroll
            for (int m = 0; m < 2; ++m)
                #pragma unroll
                for (int ot = 0; ot < 2; ++ot) acc[m][ot] = (f32x4){0.f, 0.f, 0.f, 0.f};
            const short8* src = (const short8*)H0r;
            #pragma unroll
            for (int kk = 0; kk < 8; ++kk) {
                short8 a0 = src[((bg * 2 + 0) * KS0 + 8 * wv + kk) * 64 + lane];
                short8 a1 = src[((bg * 2 + 1) * KS0 + 8 * wv + kk) * 64 + lane];
                #pragma unroll
                for (int ot = 0; ot < 2; ++ot) {
                    acc[0][ot] = __builtin_amdgcn_mfma_f32_16x16x32_bf16(a0, Wr0[ot][kk], acc[0][ot], 0, 0, 0);
                    acc[1][ot] = __builtin_amdgcn_mfma_f32_16x16x32_bf16(a1, Wr0[ot][kk], acc[1][ot], 0, 0, 0);
                }
            }
            #pragma unroll
            for (int m = 0; m < 2; ++m)
                #pragma unroll
                for (int ot = 0; ot < 2; ++ot) {
                    int base = ((wv * 2 + m) * 2 + ot) * 272 + (lane & 15) * 17 + (lane >> 4) * 4;
                    #pragma unroll
                    for (int r = 0; r < 4; ++r) red[base + r] = acc[m][ot][r];
                }
            __syncthreads();
            float xv[8];
            if (t < ENC) {
                int b = bg * 32 + bl;
                #pragma unroll
                for (int d = 0; d < 8; ++d) xv[d] = inp[(b * TT + t) * DD + d];
            } else {
                #pragma unroll
                for (int d = 0; d < 8; ++d) xv[d] = h2x[bl * 9 + d];
            }
            float g4[4];
            #pragma unroll
            for (int g = 0; g < 4; ++g) {
                int rr = u * 4 + g, ot = rr >> 4, rr16 = rr & 15;
                float s = b0r[g];
                #pragma unroll
                for (int w2 = 0; w2 < 4; ++w2)
                    s += red[((w2 * 2 + mtl) * 2 + ot) * 272 + rr16 * 17 + m16];
                #pragma unroll
                for (int d = 0; d < 8; ++d) s += wih0r[g][d] * xv[d];
                g4[g] = s;
            }
            c0r = sigm(g4[1]) * c0r + sigm(g4[0]) * tanhf(g4[2]);
            float hn = sigm(g4[3]) * tanhf(c0r);
            int b = bg * 32 + bl, k = rb * 8 + u;
            H0w[(((b >> 4) * KS0 + (k >> 5)) * 64 + ((b & 15) | (((k >> 3) & 3) << 4))) * 8 + (k & 7)] = f2bf(hn);
        }
        gbar(bar, ++ep, grp);

        // ================= P2 : layer 1 =================
        {
            f32x4 acc[2][2];
            #pragma unroll
            for (int m = 0; m < 2; ++m)
                #pragma unroll
                for (int ot = 0; ot < 2; ++ot) acc[m][ot] = (f32x4){0.f, 0.f, 0.f, 0.f};
            const short8* src = (wv < 2) ? (const short8*)H0w : (const short8*)H1r;
            const int kb = (wv & 1) * 16;
            #pragma unroll
            for (int kk = 0; kk < 16; ++kk) {
                short8 a0 = src[((bg * 2 + 0) * KS0 + kb + kk) * 64 + lane];
                short8 a1 = src[((bg * 2 + 1) * KS0 + kb + kk) * 64 + lane];
                #pragma unroll
                for (int ot = 0; ot < 2; ++ot) {
                    acc[0][ot] = __builtin_amdgcn_mfma_f32_16x16x32_bf16(a0, Wr1[ot][kk], acc[0][ot], 0, 0, 0);
                    acc[1][ot] = __builtin_amdgcn_mfma_f32_16x16x32_bf16(a1, Wr1[ot][kk], acc[1][ot], 0, 0, 0);
                }
            }
            #pragma unroll
            for (int m = 0; m < 2; ++m)
                #pragma unroll
                for (int ot = 0; ot < 2; ++ot) {
                    int base = ((wv * 2 + m) * 2 + ot) * 272 + (lane & 15) * 17 + (lane >> 4) * 4;
                    #pragma unroll
                    for (int r = 0; r < 4; ++r) red[base + r] = acc[m][ot][r];
                }
            __syncthreads();
            float g4[4];
            #pragma unroll
            for (int g = 0; g < 4; ++g) {
                int rr = u * 4 + g, ot = rr >> 4, rr16 = rr & 15;
                float s = b1r[g];
                #pragma unroll
                for (int w2 = 0; w2 < 4; ++w2)
                    s += red[((w2 * 2 + mtl) * 2 + ot) * 272 + rr16 * 17 + m16];
                g4[g] = s;
            }
            c1r = sigm(g4[1]) * c1r + sigm(g4[0]) * tanhf(g4[2]);
            float hn = sigm(g4[3]) * tanhf(c1r);
            int b = bg * 32 + bl, k = rb * 8 + u;
            H1w[(((b >> 4) * KS0 + (k >> 5)) * 64 + ((b & 15) | (((k >> 3) & 3) << 4))) * 8 + (k & 7)] = f2bf(hn);
        }
        gbar(bar, ++ep, grp);

        // ================= P3 : layer 2 (replicated per block) =================
        {
            f32x4 acc[2][2];
            #pragma unroll
            for (int m = 0; m < 2; ++m)
                #pragma unroll
                for (int ot = 0; ot < 2; ++ot) acc[m][ot] = (f32x4){0.f, 0.f, 0.f, 0.f};
            const short8* src = (const short8*)H1w;
            #pragma unroll
            for (int kk = 0; kk < 8; ++kk) {
                short8 a0 = src[((bg * 2 + 0) * KS0 + 8 * wv + kk) * 64 + lane];
                short8 a1 = src[((bg * 2 + 1) * KS0 + 8 * wv + kk) * 64 + lane];
                #pragma unroll
                for (int ot = 0; ot < 2; ++ot) {
                    acc[0][ot] = __builtin_amdgcn_mfma_f32_16x16x32_bf16(a0, Wr2[ot][kk], acc[0][ot], 0, 0, 0);
                    acc[1][ot] = __builtin_amdgcn_mfma_f32_16x16x32_bf16(a1, Wr2[ot][kk], acc[1][ot], 0, 0, 0);
                }
            }
            #pragma unroll
            for (int m = 0; m < 2; ++m)
                #pragma unroll
                for (int ot = 0; ot < 2; ++ot) {
                    int base = ((wv * 2 + m) * 2 + ot) * 272 + (lane & 15) * 17 + (lane >> 4) * 4;
                    #pragma unroll
                    for (int r = 0; r < 4; ++r) red[base + r] = acc[m][ot][r];
                }
            __syncthreads();
            float xo[8];
            #pragma unroll
            for (int d = 0; d < 8; ++d) xo[d] = h2x[bl * 9 + d];
            float g4[4];
            #pragma unroll
            for (int g = 0; g < 4; ++g) {
                int rr = u * 4 + g, ot = rr >> 4, rr16 = rr & 15;
                float s = b2r[g];
                #pragma unroll
                for (int w2 = 0; w2 < 4; ++w2)
                    s += red[((w2 * 2 + mtl) * 2 + ot) * 272 + rr16 * 17 + m16];
                #pragma unroll
                for (int d = 0; d < 8; ++d) s += whh2r[g][d] * xo[d];
                g4[g] = s;
            }
            float cn = sigm(g4[1]) * c2r + sigm(g4[0]) * tanhf(g4[2]);
            c2r = cn;
            float hn = sigm(g4[3]) * tanhf(cn);
            __syncthreads();
            h2x[bl * 9 + u] = hn;
            if (rb == 0 && t >= ENC - 1)
                pred[((bg * 32 + bl) * HOR + (t - (ENC - 1))) * DD + u] = hn;
        }
    }
}

// ---------------- host ----------------

extern "C" void kernel_launch(void* const* d_in, const int* in_sizes, int n_in,
                              void* d_out, int out_size, void* d_ws, size_t ws_size,
                              hipStream_t stream)
{
    const float* inp  = (const float*)d_in[0];
    const float* wih0 = (const float*)d_in[1];
    const float* whh0 = (const float*)d_in[2];
    const float* b0v  = (const float*)d_in[3];
    const float* wih1 = (const float*)d_in[4];
    const float* whh1 = (const float*)d_in[5];
    const float* b1v  = (const float*)d_in[6];
    const float* wih2 = (const float*)d_in[7];
    const float* whh2 = (const float*)d_in[8];
    const float* b2v  = (const float*)d_in[9];
    float* out = (float*)d_out;   // pred[172032] | y[172032] | loss[8]

    char* base = (char*)d_ws;
    size_t off = 0;
    auto carve = [&](size_t bytes) -> void* {
        void* p = base + off;
        off += (bytes + 255) & ~((size_t)255);
        return p;
    };
    unsigned short* Wp0 = (unsigned short*)carve((size_t)128 * 2 * KS0 * 64 * 8 * 2);
    unsigned short* Wp1 = (unsigned short*)carve((size_t)128 * 2 * KS1 * 64 * 8 * 2);
    unsigned short* Wp2 = (unsigned short*)carve((size_t)2 * KS0 * 64 * 8 * 2);
    size_t state_off = off;
    unsigned short* H0a = (unsigned short*)carve(B64 * H * 2);
    unsigned short* H0b = (unsigned short*)carve(B64 * H * 2);
    unsigned short* H1a = (unsigned short*)carve(B64 * H * 2);
    unsigned short* H1b = (unsigned short*)carve(B64 * H * 2);
    unsigned* bar = (unsigned*)carve(8192);   // 2 domains x 4KB
    size_t state_bytes = off - state_off;
    if (off > ws_size) return;

    zero_k<<<64, 256, 0, stream>>>((unsigned int*)(base + state_off), (int)(state_bytes / 4));
    pack0_k<<<2048, 256, 0, stream>>>(whh0, Wp0);
    pack1_k<<<4096, 256, 0, stream>>>(wih1, whh1, Wp1);
    pack2_k<<<32, 256, 0, stream>>>(wih2, Wp2);
    copy_y_k<<<672, 256, 0, stream>>>(inp, out + 172032);

    persist_k<<<NBLK, 256, 0, stream>>>(Wp0, Wp1, Wp2, wih0, b0v, b1v, whh2, b2v,
                                        inp, H0a, H0b, H1a, H1b, bar, out);

    loss_k<<<1, 256, 0, stream>>>(out, out + 172032, out + 344064);
}

// Round 4
// 7411.662 us; speedup vs baseline: 5.2880x; 1.7688x over previous
//
#include <hip/hip_runtime.h>
#include <math.h>

#define B64 64
#define H 1024
#define DD 8
#define ENC 96
#define HOR 336
#define TT 432
#define NSTEP 431
#define NBLK 256
#define KS0 32      // K=1024 in 32-wide chunks
#define KS1 64      // K=2048

typedef __attribute__((ext_vector_type(8))) short short8;
typedef __attribute__((ext_vector_type(4))) float f32x4;
typedef unsigned long long ull;

__device__ __forceinline__ unsigned short f2bf(float x) {
    union { float f; unsigned u; } v; v.f = x;
    unsigned r = v.u + 0x7fffu + ((v.u >> 16) & 1u);
    return (unsigned short)(r >> 16);
}
__device__ __forceinline__ float sigm(float x) { return 1.0f / (1.0f + __expf(-x)); }

// Coherent (MALL-direct, sc0 sc1) 16B load as 2x8B relaxed agent atomics.
// No cache-maintenance instructions are ever generated for these.
__device__ __forceinline__ short8 cload(const unsigned short* p) {
    const ull* q = (const ull*)p;
    ull lo = __hip_atomic_load(q,     __ATOMIC_RELAXED, __HIP_MEMORY_SCOPE_AGENT);
    ull hi = __hip_atomic_load(q + 1, __ATOMIC_RELAXED, __HIP_MEMORY_SCOPE_AGENT);
    union { ull u[2]; short8 s; } v; v.u[0] = lo; v.u[1] = hi;
    return v.s;
}
__device__ __forceinline__ void cstore8(ull* p, ull v) {
    __hip_atomic_store(p, v, __ATOMIC_RELAXED, __HIP_MEMORY_SCOPE_AGENT);
}

// ---------------- prep kernels (verified) ----------------

__global__ void zero_k(unsigned int* __restrict__ p, int n) {
    for (int i = blockIdx.x * 256 + threadIdx.x; i < n; i += gridDim.x * 256) p[i] = 0u;
}

__global__ void pack0_k(const float* __restrict__ w, unsigned short* __restrict__ dst) {
    const int total = 128 * 2 * KS0 * 64 * 8;
    for (int idx = blockIdx.x * 256 + threadIdx.x; idx < total; idx += gridDim.x * 256) {
        int j = idx & 7, lane = (idx >> 3) & 63, ks = (idx >> 9) & 31, nt = (idx >> 14) & 1, nb = idx >> 15;
        int rr = nt * 16 + (lane & 15);
        int row = nb * 8 + (rr >> 2) + 1024 * (rr & 3);
        int k = ks * 32 + ((lane >> 4) << 3) + j;
        dst[idx] = f2bf(w[row * 1024 + k]);
    }
}

__global__ void pack1_k(const float* __restrict__ wih, const float* __restrict__ whh,
                        unsigned short* __restrict__ dst) {
    const int total = 128 * 2 * KS1 * 64 * 8;
    for (int idx = blockIdx.x * 256 + threadIdx.x; idx < total; idx += gridDim.x * 256) {
        int j = idx & 7, lane = (idx >> 3) & 63, ks = (idx >> 9) & 63, nt = (idx >> 15) & 1, nb = idx >> 16;
        int rr = nt * 16 + (lane & 15);
        int row = nb * 8 + (rr >> 2) + 1024 * (rr & 3);
        int k = ks * 32 + ((lane >> 4) << 3) + j;
        float v = (k < 1024) ? wih[row * 1024 + k] : whh[row * 1024 + (k - 1024)];
        dst[idx] = f2bf(v);
    }
}

__global__ void pack2_k(const float* __restrict__ w, unsigned short* __restrict__ dst) {
    const int total = 2 * KS0 * 64 * 8;
    for (int idx = blockIdx.x * 256 + threadIdx.x; idx < total; idx += gridDim.x * 256) {
        int j = idx & 7, lane = (idx >> 3) & 63, ks = (idx >> 9) & 31, nt = (idx >> 14) & 1;
        int rr = nt * 16 + (lane & 15);
        int row = (rr >> 2) + 8 * (rr & 3);
        int k = ks * 32 + ((lane >> 4) << 3) + j;
        dst[idx] = f2bf(w[row * 1024 + k]);
    }
}

__global__ void copy_y_k(const float* __restrict__ inp, float* __restrict__ y) {
    const int total = B64 * HOR * DD;
    for (int i = blockIdx.x * 256 + threadIdx.x; i < total; i += gridDim.x * 256) {
        int b = i / (HOR * DD);
        int rem = i - b * (HOR * DD);
        y[i] = inp[b * (TT * DD) + ENC * DD + rem];
    }
}

__global__ void loss_k(const float* __restrict__ pred, const float* __restrict__ y,
                       float* __restrict__ loss) {
    __shared__ float part[256];
    int tid = threadIdx.x;
    int dd = tid & 7, cc = tid >> 3;
    float s = 0.f;
    for (int i = cc; i < B64 * HOR; i += 32) {
        float d = pred[i * 8 + dd] - y[i * 8 + dd];
        s += d * d;
    }
    part[tid] = s;
    __syncthreads();
    if (tid < 8) {
        float t = 0.f;
        for (int r = 0; r < 32; ++r) t += part[r * 8 + tid];
        loss[tid] = t / (float)(B64 * HOR);
    }
}

// ---------------- grid barrier: fence-free (all traffic is MALL-coherent) ----
// Per-domain layout (uints): bar[64*g] g<8 group counters, bar[512] root,
// bar[520] release word. 128 blocks/domain = 8 groups x 16.
__device__ __forceinline__ void gbar(unsigned* bar, unsigned ep, unsigned grp) {
    __syncthreads();     // each wave drains vmcnt(0) -> all sc1 stores at MALL
    if (threadIdx.x == 0) {
        __atomic_signal_fence(__ATOMIC_SEQ_CST);
        unsigned v = __hip_atomic_fetch_add(&bar[64 * grp], 1u, __ATOMIC_RELAXED,
                                            __HIP_MEMORY_SCOPE_AGENT) + 1u;
        if (v == 16u * ep) {
            unsigned r = __hip_atomic_fetch_add(&bar[512], 1u, __ATOMIC_RELAXED,
                                                __HIP_MEMORY_SCOPE_AGENT) + 1u;
            if (r == 8u * ep)
                __hip_atomic_store(&bar[520], ep, __ATOMIC_RELAXED, __HIP_MEMORY_SCOPE_AGENT);
        }
        while (__hip_atomic_load(&bar[520], __ATOMIC_RELAXED, __HIP_MEMORY_SCOPE_AGENT) < ep)
            __builtin_amdgcn_s_sleep(1);
        __atomic_signal_fence(__ATOMIC_SEQ_CST);
    }
    __syncthreads();
}

// ---------------- persistent recurrence kernel ----------------
__global__ __launch_bounds__(256, 1) void persist_k(
    const unsigned short* __restrict__ Wp0,
    const unsigned short* __restrict__ Wp1,
    const unsigned short* __restrict__ Wp2,
    const float* __restrict__ wih0, const float* __restrict__ b0v,
    const float* __restrict__ b1v,
    const float* __restrict__ whh2, const float* __restrict__ b2v,
    const float* __restrict__ inp,
    unsigned short* __restrict__ H0a, unsigned short* __restrict__ H0b,
    unsigned short* __restrict__ H1a, unsigned short* __restrict__ H1b,
    unsigned* __restrict__ bar0, float* __restrict__ pred)
{
    const int tid = threadIdx.x;
    const int wv = tid >> 6, lane = tid & 63;
    const int blk = blockIdx.x;
    const int bg = blk & 1, rb = blk >> 1;
    const int bl = tid & 31, u = tid >> 5;
    const int mtl = bl >> 4, m16 = bl & 15;
    unsigned* bar = bar0 + (bg << 10);       // independent barrier domain per batch-half
    const unsigned grp = (unsigned)(rb & 7);

    __shared__ float red[16 * 272];
    __shared__ float h2x[32 * 9];
    __shared__ ull hstage[32][2];            // 32 batches x 8 bf16 staging for 16B stores

    for (int i = tid; i < 32 * 9; i += 256) h2x[i] = 0.f;

    // 16B-chunk index (in short8 units) of (b, k=rb*8..rb*8+7) in afrag layout
    // afrag(b,k): chunk = ((b>>4)*KS0 + (rb>>2))*64 + ((b&15)|((rb&3)<<4))
    // (identical for H0 and H1: both are K=1024 / KS0 layouts)

    // ---- weights -> registers (read exactly once, normal cached loads) ----
    short8 Wr0[2][8], Wr1[2][16], Wr2[2][8];
    {
        const short8* p0 = (const short8*)Wp0;
        const short8* p1 = (const short8*)Wp1;
        const short8* p2 = (const short8*)Wp2;
        #pragma unroll
        for (int ot = 0; ot < 2; ++ot) {
            #pragma unroll
            for (int kk = 0; kk < 8; ++kk)
                Wr0[ot][kk] = p0[((rb * 2 + ot) * KS0 + (8 * wv + kk)) * 64 + lane];
            #pragma unroll
            for (int kk = 0; kk < 16; ++kk)
                Wr1[ot][kk] = p1[((rb * 2 + ot) * KS1 + (16 * wv + kk)) * 64 + lane];
            #pragma unroll
            for (int kk = 0; kk < 8; ++kk)
                Wr2[ot][kk] = p2[(ot * KS0 + (8 * wv + kk)) * 64 + lane];
        }
    }
    float wih0r[4][8], whh2r[4][8], b0r[4], b1r[4], b2r[4];
    #pragma unroll
    for (int g = 0; g < 4; ++g) {
        int row = rb * 8 + u + 1024 * g;
        #pragma unroll
        for (int d = 0; d < 8; ++d) wih0r[g][d] = wih0[row * 8 + d];
        b0r[g] = b0v[row];
        b1r[g] = b1v[row];
        int row2 = u + 8 * g;
        #pragma unroll
        for (int d = 0; d < 8; ++d) whh2r[g][d] = whh2[row2 * 8 + d];
        b2r[g] = b2v[row2];
    }
    float c0r = 0.f, c1r = 0.f, c2r = 0.f;
    unsigned ep = 0;
    __syncthreads();

    for (int t = 0; t < NSTEP; ++t) {
        const int par = t & 1;
        unsigned short* H0w = par ? H0b : H0a;
        const unsigned short* H0r = par ? H0a : H0b;
        unsigned short* H1w = par ? H1b : H1a;
        const unsigned short* H1r = par ? H1a : H1b;

        // ================= P1 : layer 0 =================
        {
            f32x4 acc[2][2];
            #pragma unroll
            for (int m = 0; m < 2; ++m)
                #pragma unroll
                for (int ot = 0; ot < 2; ++ot) acc[m][ot] = (f32x4){0.f, 0.f, 0.f, 0.f};
            #pragma unroll
            for (int kk = 0; kk < 8; ++kk) {
                short8 a0 = cload(H0r + (((bg * 2 + 0) * KS0 + 8 * wv + kk) * 64 + lane) * 8);
                short8 a1 = cload(H0r + (((bg * 2 + 1) * KS0 + 8 * wv + kk) * 64 + lane) * 8);
                #pragma unroll
                for (int ot = 0; ot < 2; ++ot) {
                    acc[0][ot] = __builtin_amdgcn_mfma_f32_16x16x32_bf16(a0, Wr0[ot][kk], acc[0][ot], 0, 0, 0);
                    acc[1][ot] = __builtin_amdgcn_mfma_f32_16x16x32_bf16(a1, Wr0[ot][kk], acc[1][ot], 0, 0, 0);
                }
            }
            #pragma unroll
            for (int m = 0; m < 2; ++m)
                #pragma unroll
                for (int ot = 0; ot < 2; ++ot) {
                    int base = ((wv * 2 + m) * 2 + ot) * 272 + (lane & 15) * 17 + (lane >> 4) * 4;
                    #pragma unroll
                    for (int r = 0; r < 4; ++r) red[base + r] = acc[m][ot][r];
                }
            __syncthreads();
            float xv[8];
            if (t < ENC) {
                int b = bg * 32 + bl;
                #pragma unroll
                for (int d = 0; d < 8; ++d) xv[d] = inp[(b * TT + t) * DD + d];
            } else {
                #pragma unroll
                for (int d = 0; d < 8; ++d) xv[d] = h2x[bl * 9 + d];
            }
            float g4[4];
            #pragma unroll
            for (int g = 0; g < 4; ++g) {
                int rr = u * 4 + g, ot = rr >> 4, rr16 = rr & 15;
                float s = b0r[g];
                #pragma unroll
                for (int w2 = 0; w2 < 4; ++w2)
                    s += red[((w2 * 2 + mtl) * 2 + ot) * 272 + rr16 * 17 + m16];
                #pragma unroll
                for (int d = 0; d < 8; ++d) s += wih0r[g][d] * xv[d];
                g4[g] = s;
            }
            c0r = sigm(g4[1]) * c0r + sigm(g4[0]) * tanhf(g4[2]);
            float hn = sigm(g4[3]) * tanhf(c0r);
            ((unsigned short*)hstage)[bl * 8 + u] = f2bf(hn);
            __syncthreads();
            if (tid < 32) {
                int b = bg * 32 + tid;
                int chunk = ((b >> 4) * KS0 + (rb >> 2)) * 64 + ((b & 15) | ((rb & 3) << 4));
                cstore8((ull*)H0w + chunk * 2,     hstage[tid][0]);
                cstore8((ull*)H0w + chunk * 2 + 1, hstage[tid][1]);
            }
        }
        gbar(bar, ++ep, grp);

        // ================= P2 : layer 1 (K = 2048 = [h0(t) | h1(t-1)]) =======
        {
            f32x4 acc[2][2];
            #pragma unroll
            for (int m = 0; m < 2; ++m)
                #pragma unroll
                for (int ot = 0; ot < 2; ++ot) acc[m][ot] = (f32x4){0.f, 0.f, 0.f, 0.f};
            const unsigned short* src = (wv < 2) ? H0w : H1r;
            const int kb = (wv & 1) * 16;
            #pragma unroll
            for (int kk = 0; kk < 16; ++kk) {
                short8 a0 = cload(src + (((bg * 2 + 0) * KS0 + kb + kk) * 64 + lane) * 8);
                short8 a1 = cload(src + (((bg * 2 + 1) * KS0 + kb + kk) * 64 + lane) * 8);
                #pragma unroll
                for (int ot = 0; ot < 2; ++ot) {
                    acc[0][ot] = __builtin_amdgcn_mfma_f32_16x16x32_bf16(a0, Wr1[ot][kk], acc[0][ot], 0, 0, 0);
                    acc[1][ot] = __builtin_amdgcn_mfma_f32_16x16x32_bf16(a1, Wr1[ot][kk], acc[1][ot], 0, 0, 0);
                }
            }
            #pragma unroll
            for (int m = 0; m < 2; ++m)
                #pragma unroll
                for (int ot = 0; ot < 2; ++ot) {
                    int base = ((wv * 2 + m) * 2 + ot) * 272 + (lane & 15) * 17 + (lane >> 4) * 4;
                    #pragma unroll
                    for (int r = 0; r < 4; ++r) red[base + r] = acc[m][ot][r];
                }
            __syncthreads();
            float g4[4];
            #pragma unroll
            for (int g = 0; g < 4; ++g) {
                int rr = u * 4 + g, ot = rr >> 4, rr16 = rr & 15;
                float s = b1r[g];
                #pragma unroll
                for (int w2 = 0; w2 < 4; ++w2)
                    s += red[((w2 * 2 + mtl) * 2 + ot) * 272 + rr16 * 17 + m16];
                g4[g] = s;
            }
            c1r = sigm(g4[1]) * c1r + sigm(g4[0]) * tanhf(g4[2]);
            float hn = sigm(g4[3]) * tanhf(c1r);
            ((unsigned short*)hstage)[bl * 8 + u] = f2bf(hn);
            __syncthreads();
            if (tid < 32) {
                int b = bg * 32 + tid;
                int chunk = ((b >> 4) * KS0 + (rb >> 2)) * 64 + ((b & 15) | ((rb & 3) << 4));
                cstore8((ull*)H1w + chunk * 2,     hstage[tid][0]);
                cstore8((ull*)H1w + chunk * 2 + 1, hstage[tid][1]);
            }
        }
        gbar(bar, ++ep, grp);

        // ================= P3 : layer 2 (replicated per block) ===============
        {
            f32x4 acc[2][2];
            #pragma unroll
            for (int m = 0; m < 2; ++m)
                #pragma unroll
                for (int ot = 0; ot < 2; ++ot) acc[m][ot] = (f32x4){0.f, 0.f, 0.f, 0.f};
            #pragma unroll
            for (int kk = 0; kk < 8; ++kk) {
                short8 a0 = cload(H1w + (((bg * 2 + 0) * KS0 + 8 * wv + kk) * 64 + lane) * 8);
                short8 a1 = cload(H1w + (((bg * 2 + 1) * KS0 + 8 * wv + kk) * 64 + lane) * 8);
                #pragma unroll
                for (int ot = 0; ot < 2; ++ot) {
                    acc[0][ot] = __builtin_amdgcn_mfma_f32_16x16x32_bf16(a0, Wr2[ot][kk], acc[0][ot], 0, 0, 0);
                    acc[1][ot] = __builtin_amdgcn_mfma_f32_16x16x32_bf16(a1, Wr2[ot][kk], acc[1][ot], 0, 0, 0);
                }
            }
            #pragma unroll
            for (int m = 0; m < 2; ++m)
                #pragma unroll
                for (int ot = 0; ot < 2; ++ot) {
                    int base = ((wv * 2 + m) * 2 + ot) * 272 + (lane & 15) * 17 + (lane >> 4) * 4;
                    #pragma unroll
                    for (int r = 0; r < 4; ++r) red[base + r] = acc[m][ot][r];
                }
            __syncthreads();
            float xo[8];
            #pragma unroll
            for (int d = 0; d < 8; ++d) xo[d] = h2x[bl * 9 + d];
            float g4[4];
            #pragma unroll
            for (int g = 0; g < 4; ++g) {
                int rr = u * 4 + g, ot = rr >> 4, rr16 = rr & 15;
                float s = b2r[g];
                #pragma unroll
                for (int w2 = 0; w2 < 4; ++w2)
                    s += red[((w2 * 2 + mtl) * 2 + ot) * 272 + rr16 * 17 + m16];
                #pragma unroll
                for (int d = 0; d < 8; ++d) s += whh2r[g][d] * xo[d];
                g4[g] = s;
            }
            float cn = sigm(g4[1]) * c2r + sigm(g4[0]) * tanhf(g4[2]);
            c2r = cn;
            float hn = sigm(g4[3]) * tanhf(cn);
            __syncthreads();
            h2x[bl * 9 + u] = hn;
            if (rb == 0 && t >= ENC - 1)
                pred[((bg * 32 + bl) * HOR + (t - (ENC - 1))) * DD + u] = hn;
        }
        // no barrier: next P1 reads only H0 (2 barriers old) + block-local LDS
    }
}

// ---------------- host ----------------

extern "C" void kernel_launch(void* const* d_in, const int* in_sizes, int n_in,
                              void* d_out, int out_size, void* d_ws, size_t ws_size,
                              hipStream_t stream)
{
    const float* inp  = (const float*)d_in[0];
    const float* wih0 = (const float*)d_in[1];
    const float* whh0 = (const float*)d_in[2];
    const float* b0v  = (const float*)d_in[3];
    const float* wih1 = (const float*)d_in[4];
    const float* whh1 = (const float*)d_in[5];
    const float* b1v  = (const float*)d_in[6];
    const float* wih2 = (const float*)d_in[7];
    const float* whh2 = (const float*)d_in[8];
    const float* b2v  = (const float*)d_in[9];
    float* out = (float*)d_out;   // pred[172032] | y[172032] | loss[8]

    char* base = (char*)d_ws;
    size_t off = 0;
    auto carve = [&](size_t bytes) -> void* {
        void* p = base + off;
        off += (bytes + 255) & ~((size_t)255);
        return p;
    };
    unsigned short* Wp0 = (unsigned short*)carve((size_t)128 * 2 * KS0 * 64 * 8 * 2);
    unsigned short* Wp1 = (unsigned short*)carve((size_t)128 * 2 * KS1 * 64 * 8 * 2);
    unsigned short* Wp2 = (unsigned short*)carve((size_t)2 * KS0 * 64 * 8 * 2);
    size_t state_off = off;
    unsigned short* H0a = (unsigned short*)carve(B64 * H * 2);
    unsigned short* H0b = (unsigned short*)carve(B64 * H * 2);
    unsigned short* H1a = (unsigned short*)carve(B64 * H * 2);
    unsigned short* H1b = (unsigned short*)carve(B64 * H * 2);
    unsigned* bar = (unsigned*)carve(8192);   // 2 domains x 4KB
    size_t state_bytes = off - state_off;
    if (off > ws_size) return;

    zero_k<<<64, 256, 0, stream>>>((unsigned int*)(base + state_off), (int)(state_bytes / 4));
    pack0_k<<<2048, 256, 0, stream>>>(whh0, Wp0);
    pack1_k<<<4096, 256, 0, stream>>>(wih1, whh1, Wp1);
    pack2_k<<<32, 256, 0, stream>>>(wih2, Wp2);
    copy_y_k<<<672, 256, 0, stream>>>(inp, out + 172032);

    persist_k<<<NBLK, 256, 0, stream>>>(Wp0, Wp1, Wp2, wih0, b0v, b1v, whh2, b2v,
                                        inp, H0a, H0b, H1a, H1b, bar, out);

    loss_k<<<1, 256, 0, stream>>>(out, out + 172032, out + 344064);
}

// Round 5
// 6453.973 us; speedup vs baseline: 6.0727x; 1.1484x over previous
//
#include <hip/hip_runtime.h>
#include <math.h>

#define B64 64
#define H 1024
#define DD 8
#define ENC 96
#define HOR 336
#define TT 432
#define NSTEP 431
#define NBLK 256
#define KS0 32      // K=1024 in 32-wide chunks
#define KS1 64      // K=2048

typedef __attribute__((ext_vector_type(8))) short short8;
typedef __attribute__((ext_vector_type(4))) float f32x4;
typedef unsigned long long ull;

__device__ __forceinline__ unsigned short f2bf(float x) {
    union { float f; unsigned u; } v; v.f = x;
    unsigned r = v.u + 0x7fffu + ((v.u >> 16) & 1u);
    return (unsigned short)(r >> 16);
}
// fast sigmoid/tanh: v_exp + v_rcp (1-ulp approx, fine vs 1e-1 threshold)
__device__ __forceinline__ float sigm(float x) {
    return __builtin_amdgcn_rcpf(1.0f + __expf(-x));
}
__device__ __forceinline__ float ftanh(float x) {
    float e = __expf(fminf(x, 10.0f) * 2.0f);   // clamp: avoid inf/inf
    return (e - 1.0f) * __builtin_amdgcn_rcpf(e + 1.0f);
}

// MALL-coherent (sc0 sc1, no cache-maintenance) 16B load / 8B store
__device__ __forceinline__ short8 cload(const unsigned short* p) {
    const ull* q = (const ull*)p;
    ull lo = __hip_atomic_load(q,     __ATOMIC_RELAXED, __HIP_MEMORY_SCOPE_AGENT);
    ull hi = __hip_atomic_load(q + 1, __ATOMIC_RELAXED, __HIP_MEMORY_SCOPE_AGENT);
    union { ull u[2]; short8 s; } v; v.u[0] = lo; v.u[1] = hi;
    return v.s;
}
__device__ __forceinline__ void cstore8(ull* p, ull v) {
    __hip_atomic_store(p, v, __ATOMIC_RELAXED, __HIP_MEMORY_SCOPE_AGENT);
}

// ---------------- prep kernels (verified) ----------------

__global__ void zero_k(unsigned int* __restrict__ p, int n) {
    for (int i = blockIdx.x * 256 + threadIdx.x; i < n; i += gridDim.x * 256) p[i] = 0u;
}

__global__ void pack0_k(const float* __restrict__ w, unsigned short* __restrict__ dst) {
    const int total = 128 * 2 * KS0 * 64 * 8;
    for (int idx = blockIdx.x * 256 + threadIdx.x; idx < total; idx += gridDim.x * 256) {
        int j = idx & 7, lane = (idx >> 3) & 63, ks = (idx >> 9) & 31, nt = (idx >> 14) & 1, nb = idx >> 15;
        int rr = nt * 16 + (lane & 15);
        int row = nb * 8 + (rr >> 2) + 1024 * (rr & 3);
        int k = ks * 32 + ((lane >> 4) << 3) + j;
        dst[idx] = f2bf(w[row * 1024 + k]);
    }
}

__global__ void pack1_k(const float* __restrict__ wih, const float* __restrict__ whh,
                        unsigned short* __restrict__ dst) {
    const int total = 128 * 2 * KS1 * 64 * 8;
    for (int idx = blockIdx.x * 256 + threadIdx.x; idx < total; idx += gridDim.x * 256) {
        int j = idx & 7, lane = (idx >> 3) & 63, ks = (idx >> 9) & 63, nt = (idx >> 15) & 1, nb = idx >> 16;
        int rr = nt * 16 + (lane & 15);
        int row = nb * 8 + (rr >> 2) + 1024 * (rr & 3);
        int k = ks * 32 + ((lane >> 4) << 3) + j;
        float v = (k < 1024) ? wih[row * 1024 + k] : whh[row * 1024 + (k - 1024)];
        dst[idx] = f2bf(v);
    }
}

__global__ void pack2_k(const float* __restrict__ w, unsigned short* __restrict__ dst) {
    const int total = 2 * KS0 * 64 * 8;
    for (int idx = blockIdx.x * 256 + threadIdx.x; idx < total; idx += gridDim.x * 256) {
        int j = idx & 7, lane = (idx >> 3) & 63, ks = (idx >> 9) & 31, nt = (idx >> 14) & 1;
        int rr = nt * 16 + (lane & 15);
        int row = (rr >> 2) + 8 * (rr & 3);
        int k = ks * 32 + ((lane >> 4) << 3) + j;
        dst[idx] = f2bf(w[row * 1024 + k]);
    }
}

__global__ void copy_y_k(const float* __restrict__ inp, float* __restrict__ y) {
    const int total = B64 * HOR * DD;
    for (int i = blockIdx.x * 256 + threadIdx.x; i < total; i += gridDim.x * 256) {
        int b = i / (HOR * DD);
        int rem = i - b * (HOR * DD);
        y[i] = inp[b * (TT * DD) + ENC * DD + rem];
    }
}

__global__ void loss_k(const float* __restrict__ pred, const float* __restrict__ y,
                       float* __restrict__ loss) {
    __shared__ float part[256];
    int tid = threadIdx.x;
    int dd = tid & 7, cc = tid >> 3;
    float s = 0.f;
    for (int i = cc; i < B64 * HOR; i += 32) {
        float d = pred[i * 8 + dd] - y[i * 8 + dd];
        s += d * d;
    }
    part[tid] = s;
    __syncthreads();
    if (tid < 8) {
        float t = 0.f;
        for (int r = 0; r < 32; ++r) t += part[r * 8 + tid];
        loss[tid] = t / (float)(B64 * HOR);
    }
}

// ---- flag-array grid barrier: no RMWs, no hot line ----
// dom layout (uints): flags[rb*32] rb<128 (128B stride), rel at dom+4096+i*32 i<8.
// Root block (rb==0): wave 0 sweeps all 128 flags with 2 lane-parallel loads,
// then broadcasts epoch to 8 release lines (16 pollers each).
__device__ __forceinline__ void gbar(unsigned* dom, int rb, unsigned ep) {
    __syncthreads();                 // per-wave vmcnt(0): data stores at MALL
    const int tid = threadIdx.x;
    if (rb == 0) {
        if (tid < 64) {
            if (tid == 0)
                __hip_atomic_store(dom, ep, __ATOMIC_RELAXED, __HIP_MEMORY_SCOPE_AGENT);
            const unsigned* f0 = dom + tid * 32;
            const unsigned* f1 = dom + (tid + 64) * 32;
            for (;;) {
                unsigned a = __hip_atomic_load(f0, __ATOMIC_RELAXED, __HIP_MEMORY_SCOPE_AGENT);
                unsigned b = __hip_atomic_load(f1, __ATOMIC_RELAXED, __HIP_MEMORY_SCOPE_AGENT);
                if (__all((a >= ep) && (b >= ep))) break;
                __builtin_amdgcn_s_sleep(1);
            }
            if (tid < 8)
                __hip_atomic_store(dom + 4096 + tid * 32, ep, __ATOMIC_RELAXED, __HIP_MEMORY_SCOPE_AGENT);
        }
    } else if (tid == 0) {
        __hip_atomic_store(dom + rb * 32, ep, __ATOMIC_RELAXED, __HIP_MEMORY_SCOPE_AGENT);
        const unsigned* r = dom + 4096 + (rb & 7) * 32;
        while (__hip_atomic_load(r, __ATOMIC_RELAXED, __HIP_MEMORY_SCOPE_AGENT) < ep)
            __builtin_amdgcn_s_sleep(1);
    }
    __syncthreads();
}

// ---------------- persistent recurrence kernel ----------------
__global__ __launch_bounds__(256, 1) void persist_k(
    const unsigned short* __restrict__ Wp0,
    const unsigned short* __restrict__ Wp1,
    const unsigned short* __restrict__ Wp2,
    const float* __restrict__ wih0, const float* __restrict__ b0v,
    const float* __restrict__ b1v,
    const float* __restrict__ whh2, const float* __restrict__ b2v,
    const float* __restrict__ inp,
    unsigned short* __restrict__ H0a, unsigned short* __restrict__ H0b,
    unsigned short* __restrict__ H1a, unsigned short* __restrict__ H1b,
    unsigned* __restrict__ bar0, float* __restrict__ pred)
{
    const int tid = threadIdx.x;
    const int wv = tid >> 6, lane = tid & 63;
    const int blk = blockIdx.x;
    const int bg = blk & 1, rb = blk >> 1;
    const int bl = tid & 31, u = tid >> 5;
    const int mtl = bl >> 4, m16 = bl & 15;
    unsigned* dom = bar0 + (bg << 13);      // 32KB per barrier domain

    __shared__ float red[16 * 272];
    __shared__ float h2x[32 * 9];
    __shared__ ull hstage[32][2];

    for (int i = tid; i < 32 * 9; i += 256) h2x[i] = 0.f;

    // ---- weights -> registers (read once, cached loads) ----
    short8 Wr0[2][8], Wr1[2][16], Wr2[2][8];
    {
        const short8* p0 = (const short8*)Wp0;
        const short8* p1 = (const short8*)Wp1;
        const short8* p2 = (const short8*)Wp2;
        #pragma unroll
        for (int ot = 0; ot < 2; ++ot) {
            #pragma unroll
            for (int kk = 0; kk < 8; ++kk)
                Wr0[ot][kk] = p0[((rb * 2 + ot) * KS0 + (8 * wv + kk)) * 64 + lane];
            #pragma unroll
            for (int kk = 0; kk < 16; ++kk)
                Wr1[ot][kk] = p1[((rb * 2 + ot) * KS1 + (16 * wv + kk)) * 64 + lane];
            #pragma unroll
            for (int kk = 0; kk < 8; ++kk)
                Wr2[ot][kk] = p2[(ot * KS0 + (8 * wv + kk)) * 64 + lane];
        }
    }
    float wih0r[4][8], whh2r[4][8], b0r[4], b1r[4], b2r[4];
    #pragma unroll
    for (int g = 0; g < 4; ++g) {
        int row = rb * 8 + u + 1024 * g;
        #pragma unroll
        for (int d = 0; d < 8; ++d) wih0r[g][d] = wih0[row * 8 + d];
        b0r[g] = b0v[row];
        b1r[g] = b1v[row];
        int row2 = u + 8 * g;
        #pragma unroll
        for (int d = 0; d < 8; ++d) whh2r[g][d] = whh2[row2 * 8 + d];
        b2r[g] = b2v[row2];
    }
    float c0r = 0.f, c1r = 0.f, c2r = 0.f;
    unsigned ep = 0;
    short8 p1a[8], p1b[8];                  // prefetched P1 A-fragments
    __syncthreads();

    // ---- P1 load: H0(tt-1) fragments -> registers ----
    auto loadP1 = [&](int tt) {
        const unsigned short* Hr = (tt & 1) ? H0a : H0b;
        #pragma unroll
        for (int kk = 0; kk < 8; ++kk) {
            p1a[kk] = cload(Hr + (((bg * 2 + 0) * KS0 + 8 * wv + kk) * 64 + lane) * 8);
            p1b[kk] = cload(Hr + (((bg * 2 + 1) * KS0 + 8 * wv + kk) * 64 + lane) * 8);
        }
    };
    // ---- P1 compute: layer-0 GEMM + cell, store h0(tt) ----
    auto runP1 = [&](int tt) {
        unsigned short* Hw = (tt & 1) ? H0b : H0a;
        f32x4 acc[2][2];
        #pragma unroll
        for (int m = 0; m < 2; ++m)
            #pragma unroll
            for (int ot = 0; ot < 2; ++ot) acc[m][ot] = (f32x4){0.f, 0.f, 0.f, 0.f};
        #pragma unroll
        for (int kk = 0; kk < 8; ++kk) {
            #pragma unroll
            for (int ot = 0; ot < 2; ++ot) {
                acc[0][ot] = __builtin_amdgcn_mfma_f32_16x16x32_bf16(p1a[kk], Wr0[ot][kk], acc[0][ot], 0, 0, 0);
                acc[1][ot] = __builtin_amdgcn_mfma_f32_16x16x32_bf16(p1b[kk], Wr0[ot][kk], acc[1][ot], 0, 0, 0);
            }
        }
        #pragma unroll
        for (int m = 0; m < 2; ++m)
            #pragma unroll
            for (int ot = 0; ot < 2; ++ot) {
                int base = ((wv * 2 + m) * 2 + ot) * 272 + (lane & 15) * 17 + (lane >> 4) * 4;
                #pragma unroll
                for (int r = 0; r < 4; ++r) red[base + r] = acc[m][ot][r];
            }
        __syncthreads();
        float xv[8];
        if (tt < ENC) {
            int b = bg * 32 + bl;
            #pragma unroll
            for (int d = 0; d < 8; ++d) xv[d] = inp[(b * TT + tt) * DD + d];
        } else {
            #pragma unroll
            for (int d = 0; d < 8; ++d) xv[d] = h2x[bl * 9 + d];
        }
        float g4[4];
        #pragma unroll
        for (int g = 0; g < 4; ++g) {
            int rr = u * 4 + g, ot = rr >> 4, rr16 = rr & 15;
            float s = b0r[g];
            #pragma unroll
            for (int w2 = 0; w2 < 4; ++w2)
                s += red[((w2 * 2 + mtl) * 2 + ot) * 272 + rr16 * 17 + m16];
            #pragma unroll
            for (int d = 0; d < 8; ++d) s += wih0r[g][d] * xv[d];
            g4[g] = s;
        }
        c0r = sigm(g4[1]) * c0r + sigm(g4[0]) * ftanh(g4[2]);
        float hn = sigm(g4[3]) * ftanh(c0r);
        ((unsigned short*)hstage)[bl * 8 + u] = f2bf(hn);
        __syncthreads();
        if (tid < 32) {
            int b = bg * 32 + tid;
            int chunk = ((b >> 4) * KS0 + (rb >> 2)) * 64 + ((b & 15) | ((rb & 3) << 4));
            cstore8((ull*)Hw + chunk * 2,     hstage[tid][0]);
            cstore8((ull*)Hw + chunk * 2 + 1, hstage[tid][1]);
        }
    };

    // ---- preamble: P1(0) ----
    loadP1(0);
    runP1(0);
    gbar(dom, rb, ++ep);

    for (int t = 0; t < NSTEP; ++t) {
        const int par = t & 1;
        unsigned short* H0w = par ? H0b : H0a;
        unsigned short* H1w = par ? H1b : H1a;
        const unsigned short* H1r = par ? H1a : H1b;

        // ================= P2 : layer 1 (K = 2048 = [h0(t) | h1(t-1)]) =======
        {
            f32x4 acc[2][2];
            #pragma unroll
            for (int m = 0; m < 2; ++m)
                #pragma unroll
                for (int ot = 0; ot < 2; ++ot) acc[m][ot] = (f32x4){0.f, 0.f, 0.f, 0.f};
            const unsigned short* src = (wv < 2) ? H0w : H1r;
            const int kb = (wv & 1) * 16;
            #pragma unroll
            for (int kk = 0; kk < 16; ++kk) {
                short8 a0 = cload(src + (((bg * 2 + 0) * KS0 + kb + kk) * 64 + lane) * 8);
                short8 a1 = cload(src + (((bg * 2 + 1) * KS0 + kb + kk) * 64 + lane) * 8);
                #pragma unroll
                for (int ot = 0; ot < 2; ++ot) {
                    acc[0][ot] = __builtin_amdgcn_mfma_f32_16x16x32_bf16(a0, Wr1[ot][kk], acc[0][ot], 0, 0, 0);
                    acc[1][ot] = __builtin_amdgcn_mfma_f32_16x16x32_bf16(a1, Wr1[ot][kk], acc[1][ot], 0, 0, 0);
                }
            }
            #pragma unroll
            for (int m = 0; m < 2; ++m)
                #pragma unroll
                for (int ot = 0; ot < 2; ++ot) {
                    int base = ((wv * 2 + m) * 2 + ot) * 272 + (lane & 15) * 17 + (lane >> 4) * 4;
                    #pragma unroll
                    for (int r = 0; r < 4; ++r) red[base + r] = acc[m][ot][r];
                }
            __syncthreads();
            float g4[4];
            #pragma unroll
            for (int g = 0; g < 4; ++g) {
                int rr = u * 4 + g, ot = rr >> 4, rr16 = rr & 15;
                float s = b1r[g];
                #pragma unroll
                for (int w2 = 0; w2 < 4; ++w2)
                    s += red[((w2 * 2 + mtl) * 2 + ot) * 272 + rr16 * 17 + m16];
                g4[g] = s;
            }
            c1r = sigm(g4[1]) * c1r + sigm(g4[0]) * ftanh(g4[2]);
            float hn = sigm(g4[3]) * ftanh(c1r);
            ((unsigned short*)hstage)[bl * 8 + u] = f2bf(hn);
            __syncthreads();
            if (tid < 32) {
                int b = bg * 32 + tid;
                int chunk = ((b >> 4) * KS0 + (rb >> 2)) * 64 + ((b & 15) | ((rb & 3) << 4));
                cstore8((ull*)H1w + chunk * 2,     hstage[tid][0]);
                cstore8((ull*)H1w + chunk * 2 + 1, hstage[tid][1]);
            }
        }
        gbar(dom, rb, ++ep);

        // ============ merged window: prefetch P1(t+1), P3(t), run P1(t+1) ====
        if (t < NSTEP - 1) loadP1(t + 1);   // overlaps P3's MALL latency

        {   // P3 : layer 2 (replicated per block)
            f32x4 acc[2][2];
            #pragma unroll
            for (int m = 0; m < 2; ++m)
                #pragma unroll
                for (int ot = 0; ot < 2; ++ot) acc[m][ot] = (f32x4){0.f, 0.f, 0.f, 0.f};
            #pragma unroll
            for (int kk = 0; kk < 8; ++kk) {
                short8 a0 = cload(H1w + (((bg * 2 + 0) * KS0 + 8 * wv + kk) * 64 + lane) * 8);
                short8 a1 = cload(H1w + (((bg * 2 + 1) * KS0 + 8 * wv + kk) * 64 + lane) * 8);
                #pragma unroll
                for (int ot = 0; ot < 2; ++ot) {
                    acc[0][ot] = __builtin_amdgcn_mfma_f32_16x16x32_bf16(a0, Wr2[ot][kk], acc[0][ot], 0, 0, 0);
                    acc[1][ot] = __builtin_amdgcn_mfma_f32_16x16x32_bf16(a1, Wr2[ot][kk], acc[1][ot], 0, 0, 0);
                }
            }
            #pragma unroll
            for (int m = 0; m < 2; ++m)
                #pragma unroll
                for (int ot = 0; ot < 2; ++ot) {
                    int base = ((wv * 2 + m) * 2 + ot) * 272 + (lane & 15) * 17 + (lane >> 4) * 4;
                    #pragma unroll
                    for (int r = 0; r < 4; ++r) red[base + r] = acc[m][ot][r];
                }
            __syncthreads();
            float xo[8];
            #pragma unroll
            for (int d = 0; d < 8; ++d) xo[d] = h2x[bl * 9 + d];
            float g4[4];
            #pragma unroll
            for (int g = 0; g < 4; ++g) {
                int rr = u * 4 + g, ot = rr >> 4, rr16 = rr & 15;
                float s = b2r[g];
                #pragma unroll
                for (int w2 = 0; w2 < 4; ++w2)
                    s += red[((w2 * 2 + mtl) * 2 + ot) * 272 + rr16 * 17 + m16];
                #pragma unroll
                for (int d = 0; d < 8; ++d) s += whh2r[g][d] * xo[d];
                g4[g] = s;
            }
            float cn = sigm(g4[1]) * c2r + sigm(g4[0]) * ftanh(g4[2]);
            c2r = cn;
            float hn = sigm(g4[3]) * ftanh(cn);
            __syncthreads();               // old-h2x reads done before overwrite
            h2x[bl * 9 + u] = hn;
            if (rb == 0 && t >= ENC - 1)
                pred[((bg * 32 + bl) * HOR + (t - (ENC - 1))) * DD + u] = hn;
        }

        if (t < NSTEP - 1) {
            runP1(t + 1);                  // red reuse safe: P3's 2nd sync passed
            gbar(dom, rb, ++ep);
        }
    }
}

// ---------------- host ----------------

extern "C" void kernel_launch(void* const* d_in, const int* in_sizes, int n_in,
                              void* d_out, int out_size, void* d_ws, size_t ws_size,
                              hipStream_t stream)
{
    const float* inp  = (const float*)d_in[0];
    const float* wih0 = (const float*)d_in[1];
    const float* whh0 = (const float*)d_in[2];
    const float* b0v  = (const float*)d_in[3];
    const float* wih1 = (const float*)d_in[4];
    const float* whh1 = (const float*)d_in[5];
    const float* b1v  = (const float*)d_in[6];
    const float* wih2 = (const float*)d_in[7];
    const float* whh2 = (const float*)d_in[8];
    const float* b2v  = (const float*)d_in[9];
    float* out = (float*)d_out;   // pred[172032] | y[172032] | loss[8]

    char* base = (char*)d_ws;
    size_t off = 0;
    auto carve = [&](size_t bytes) -> void* {
        void* p = base + off;
        off += (bytes + 255) & ~((size_t)255);
        return p;
    };
    unsigned short* Wp0 = (unsigned short*)carve((size_t)128 * 2 * KS0 * 64 * 8 * 2);
    unsigned short* Wp1 = (unsigned short*)carve((size_t)128 * 2 * KS1 * 64 * 8 * 2);
    unsigned short* Wp2 = (unsigned short*)carve((size_t)2 * KS0 * 64 * 8 * 2);
    size_t state_off = off;
    unsigned short* H0a = (unsigned short*)carve(B64 * H * 2);
    unsigned short* H0b = (unsigned short*)carve(B64 * H * 2);
    unsigned short* H1a = (unsigned short*)carve(B64 * H * 2);
    unsigned short* H1b = (unsigned short*)carve(B64 * H * 2);
    unsigned* bar = (unsigned*)carve(2 * 8192 * 4);   // 2 domains x 32KB (flags+rel)
    size_t state_bytes = off - state_off;
    if (off > ws_size) return;

    zero_k<<<64, 256, 0, stream>>>((unsigned int*)(base + state_off), (int)(state_bytes / 4));
    pack0_k<<<2048, 256, 0, stream>>>(whh0, Wp0);
    pack1_k<<<4096, 256, 0, stream>>>(wih1, whh1, Wp1);
    pack2_k<<<32, 256, 0, stream>>>(wih2, Wp2);
    copy_y_k<<<672, 256, 0, stream>>>(inp, out + 172032);

    persist_k<<<NBLK, 256, 0, stream>>>(Wp0, Wp1, Wp2, wih0, b0v, b1v, whh2, b2v,
                                        inp, H0a, H0b, H1a, H1b, bar, out);

    loss_k<<<1, 256, 0, stream>>>(out, out + 172032, out + 344064);
}

// Round 6
// 6320.658 us; speedup vs baseline: 6.2008x; 1.0211x over previous
//
#include <hip/hip_runtime.h>
#include <math.h>

#define B64 64
#define H 1024
#define DD 8
#define ENC 96
#define HOR 336
#define TT 432
#define NSTEP 431
#define NBLK 256
#define KS0 32      // K=1024 in 32-wide chunks
#define KS1 64      // K=2048

typedef __attribute__((ext_vector_type(8))) short short8;
typedef __attribute__((ext_vector_type(4))) float f32x4;
typedef unsigned long long ull;

__device__ __forceinline__ unsigned short f2bf(float x) {
    union { float f; unsigned u; } v; v.f = x;
    unsigned r = v.u + 0x7fffu + ((v.u >> 16) & 1u);
    return (unsigned short)(r >> 16);
}
// fast sigmoid/tanh: v_exp + v_rcp (1-ulp approx, fine vs 1e-1 threshold)
__device__ __forceinline__ float sigm(float x) {
    return __builtin_amdgcn_rcpf(1.0f + __expf(-x));
}
__device__ __forceinline__ float ftanh(float x) {
    float e = __expf(fminf(x, 10.0f) * 2.0f);   // clamp: avoid inf/inf
    return (e - 1.0f) * __builtin_amdgcn_rcpf(e + 1.0f);
}

// Agent-coherent 16B load / 8B store for H transport (L2-cached, MALL-coherent)
__device__ __forceinline__ short8 cload(const unsigned short* p) {
    const ull* q = (const ull*)p;
    ull lo = __hip_atomic_load(q,     __ATOMIC_RELAXED, __HIP_MEMORY_SCOPE_AGENT);
    ull hi = __hip_atomic_load(q + 1, __ATOMIC_RELAXED, __HIP_MEMORY_SCOPE_AGENT);
    union { ull u[2]; short8 s; } v; v.u[0] = lo; v.u[1] = hi;
    return v.s;
}
__device__ __forceinline__ void cstore8(ull* p, ull v) {
    __hip_atomic_store(p, v, __ATOMIC_RELAXED, __HIP_MEMORY_SCOPE_AGENT);
}

// ---------------- prep kernels (verified) ----------------

__global__ void zero_k(unsigned int* __restrict__ p, int n) {
    for (int i = blockIdx.x * 256 + threadIdx.x; i < n; i += gridDim.x * 256) p[i] = 0u;
}

__global__ void pack0_k(const float* __restrict__ w, unsigned short* __restrict__ dst) {
    const int total = 128 * 2 * KS0 * 64 * 8;
    for (int idx = blockIdx.x * 256 + threadIdx.x; idx < total; idx += gridDim.x * 256) {
        int j = idx & 7, lane = (idx >> 3) & 63, ks = (idx >> 9) & 31, nt = (idx >> 14) & 1, nb = idx >> 15;
        int rr = nt * 16 + (lane & 15);
        int row = nb * 8 + (rr >> 2) + 1024 * (rr & 3);
        int k = ks * 32 + ((lane >> 4) << 3) + j;
        dst[idx] = f2bf(w[row * 1024 + k]);
    }
}

__global__ void pack1_k(const float* __restrict__ wih, const float* __restrict__ whh,
                        unsigned short* __restrict__ dst) {
    const int total = 128 * 2 * KS1 * 64 * 8;
    for (int idx = blockIdx.x * 256 + threadIdx.x; idx < total; idx += gridDim.x * 256) {
        int j = idx & 7, lane = (idx >> 3) & 63, ks = (idx >> 9) & 63, nt = (idx >> 15) & 1, nb = idx >> 16;
        int rr = nt * 16 + (lane & 15);
        int row = nb * 8 + (rr >> 2) + 1024 * (rr & 3);
        int k = ks * 32 + ((lane >> 4) << 3) + j;
        float v = (k < 1024) ? wih[row * 1024 + k] : whh[row * 1024 + (k - 1024)];
        dst[idx] = f2bf(v);
    }
}

__global__ void pack2_k(const float* __restrict__ w, unsigned short* __restrict__ dst) {
    const int total = 2 * KS0 * 64 * 8;
    for (int idx = blockIdx.x * 256 + threadIdx.x; idx < total; idx += gridDim.x * 256) {
        int j = idx & 7, lane = (idx >> 3) & 63, ks = (idx >> 9) & 31, nt = (idx >> 14) & 1;
        int rr = nt * 16 + (lane & 15);
        int row = (rr >> 2) + 8 * (rr & 3);
        int k = ks * 32 + ((lane >> 4) << 3) + j;
        dst[idx] = f2bf(w[row * 1024 + k]);
    }
}

__global__ void copy_y_k(const float* __restrict__ inp, float* __restrict__ y) {
    const int total = B64 * HOR * DD;
    for (int i = blockIdx.x * 256 + threadIdx.x; i < total; i += gridDim.x * 256) {
        int b = i / (HOR * DD);
        int rem = i - b * (HOR * DD);
        y[i] = inp[b * (TT * DD) + ENC * DD + rem];
    }
}

__global__ void loss_k(const float* __restrict__ pred, const float* __restrict__ y,
                       float* __restrict__ loss) {
    __shared__ float part[256];
    int tid = threadIdx.x;
    int dd = tid & 7, cc = tid >> 3;
    float s = 0.f;
    for (int i = cc; i < B64 * HOR; i += 32) {
        float d = pred[i * 8 + dd] - y[i * 8 + dd];
        s += d * d;
    }
    part[tid] = s;
    __syncthreads();
    if (tid < 8) {
        float t = 0.f;
        for (int r = 0; r < 32; ++r) t += part[r * 8 + tid];
        loss[tid] = t / (float)(B64 * HOR);
    }
}

// ---- grid barrier v3: SYSTEM-scope (L2-bypassing) flags, all-blocks sweep ----
// dom layout (uints): flags at dom[rb*32], rb<128 (128B stride). Every block
// stores its own epoch flag, then wave 0 sweeps ALL 128 flags (64 lanes x 2
// lines) until all >= ep. No root hop, no release line, no RMWs, and the
// polls read MALL state directly (system scope) instead of waiting for an
// L2 directory-invalidate round — that invalidate round was round-5's ~5 us.
__device__ __forceinline__ void gbar(unsigned* dom, int rb, unsigned ep) {
    __syncthreads();   // each wave drains vmcnt(0): data stores visible first
    const int tid = threadIdx.x;
    if (tid < 64) {
        if (tid == 0)
            __hip_atomic_store(dom + rb * 32, ep, __ATOMIC_RELAXED,
                               __HIP_MEMORY_SCOPE_SYSTEM);
        const unsigned* f0 = dom + tid * 32;
        const unsigned* f1 = dom + (tid + 64) * 32;
        for (;;) {
            unsigned a = __hip_atomic_load(f0, __ATOMIC_RELAXED, __HIP_MEMORY_SCOPE_SYSTEM);
            unsigned b = __hip_atomic_load(f1, __ATOMIC_RELAXED, __HIP_MEMORY_SCOPE_SYSTEM);
            if (__all((a >= ep) && (b >= ep))) break;
            __builtin_amdgcn_s_sleep(1);
        }
    }
    __syncthreads();
}

// ---------------- persistent recurrence kernel ----------------
__global__ __launch_bounds__(256, 1) void persist_k(
    const unsigned short* __restrict__ Wp0,
    const unsigned short* __restrict__ Wp1,
    const unsigned short* __restrict__ Wp2,
    const float* __restrict__ wih0, const float* __restrict__ b0v,
    const float* __restrict__ b1v,
    const float* __restrict__ whh2, const float* __restrict__ b2v,
    const float* __restrict__ inp,
    unsigned short* __restrict__ H0a, unsigned short* __restrict__ H0b,
    unsigned short* __restrict__ H1a, unsigned short* __restrict__ H1b,
    unsigned* __restrict__ bar0, float* __restrict__ pred)
{
    const int tid = threadIdx.x;
    const int wv = tid >> 6, lane = tid & 63;
    const int blk = blockIdx.x;
    const int bg = blk & 1, rb = blk >> 1;
    const int bl = tid & 31, u = tid >> 5;
    const int mtl = bl >> 4, m16 = bl & 15;
    unsigned* dom = bar0 + (bg << 13);      // 32KB per barrier domain

    __shared__ float red[16 * 272];
    __shared__ float h2x[32 * 9];
    __shared__ ull hstage[32][2];

    for (int i = tid; i < 32 * 9; i += 256) h2x[i] = 0.f;

    // ---- weights -> registers (read once, cached loads) ----
    short8 Wr0[2][8], Wr1[2][16], Wr2[2][8];
    {
        const short8* p0 = (const short8*)Wp0;
        const short8* p1 = (const short8*)Wp1;
        const short8* p2 = (const short8*)Wp2;
        #pragma unroll
        for (int ot = 0; ot < 2; ++ot) {
            #pragma unroll
            for (int kk = 0; kk < 8; ++kk)
                Wr0[ot][kk] = p0[((rb * 2 + ot) * KS0 + (8 * wv + kk)) * 64 + lane];
            #pragma unroll
            for (int kk = 0; kk < 16; ++kk)
                Wr1[ot][kk] = p1[((rb * 2 + ot) * KS1 + (16 * wv + kk)) * 64 + lane];
            #pragma unroll
            for (int kk = 0; kk < 8; ++kk)
                Wr2[ot][kk] = p2[(ot * KS0 + (8 * wv + kk)) * 64 + lane];
        }
    }
    float wih0r[4][8], whh2r[4][8], b0r[4], b1r[4], b2r[4];
    #pragma unroll
    for (int g = 0; g < 4; ++g) {
        int row = rb * 8 + u + 1024 * g;
        #pragma unroll
        for (int d = 0; d < 8; ++d) wih0r[g][d] = wih0[row * 8 + d];
        b0r[g] = b0v[row];
        b1r[g] = b1v[row];
        int row2 = u + 8 * g;
        #pragma unroll
        for (int d = 0; d < 8; ++d) whh2r[g][d] = whh2[row2 * 8 + d];
        b2r[g] = b2v[row2];
    }
    float c0r = 0.f, c1r = 0.f, c2r = 0.f;
    unsigned ep = 0;
    short8 p1a[8], p1b[8];                  // prefetched P1 A-fragments
    __syncthreads();

    // ---- P1 load: H0(tt-1) fragments -> registers ----
    auto loadP1 = [&](int tt) {
        const unsigned short* Hr = (tt & 1) ? H0a : H0b;
        #pragma unroll
        for (int kk = 0; kk < 8; ++kk) {
            p1a[kk] = cload(Hr + (((bg * 2 + 0) * KS0 + 8 * wv + kk) * 64 + lane) * 8);
            p1b[kk] = cload(Hr + (((bg * 2 + 1) * KS0 + 8 * wv + kk) * 64 + lane) * 8);
        }
    };
    // ---- P1 compute: layer-0 GEMM + cell, store h0(tt) ----
    auto runP1 = [&](int tt) {
        unsigned short* Hw = (tt & 1) ? H0b : H0a;
        f32x4 acc[2][2];
        #pragma unroll
        for (int m = 0; m < 2; ++m)
            #pragma unroll
            for (int ot = 0; ot < 2; ++ot) acc[m][ot] = (f32x4){0.f, 0.f, 0.f, 0.f};
        #pragma unroll
        for (int kk = 0; kk < 8; ++kk) {
            #pragma unroll
            for (int ot = 0; ot < 2; ++ot) {
                acc[0][ot] = __builtin_amdgcn_mfma_f32_16x16x32_bf16(p1a[kk], Wr0[ot][kk], acc[0][ot], 0, 0, 0);
                acc[1][ot] = __builtin_amdgcn_mfma_f32_16x16x32_bf16(p1b[kk], Wr0[ot][kk], acc[1][ot], 0, 0, 0);
            }
        }
        #pragma unroll
        for (int m = 0; m < 2; ++m)
            #pragma unroll
            for (int ot = 0; ot < 2; ++ot) {
                int base = ((wv * 2 + m) * 2 + ot) * 272 + (lane & 15) * 17 + (lane >> 4) * 4;
                #pragma unroll
                for (int r = 0; r < 4; ++r) red[base + r] = acc[m][ot][r];
            }
        __syncthreads();
        float xv[8];
        if (tt < ENC) {
            int b = bg * 32 + bl;
            #pragma unroll
            for (int d = 0; d < 8; ++d) xv[d] = inp[(b * TT + tt) * DD + d];
        } else {
            #pragma unroll
            for (int d = 0; d < 8; ++d) xv[d] = h2x[bl * 9 + d];
        }
        float g4[4];
        #pragma unroll
        for (int g = 0; g < 4; ++g) {
            int rr = u * 4 + g, ot = rr >> 4, rr16 = rr & 15;
            float s = b0r[g];
            #pragma unroll
            for (int w2 = 0; w2 < 4; ++w2)
                s += red[((w2 * 2 + mtl) * 2 + ot) * 272 + rr16 * 17 + m16];
            #pragma unroll
            for (int d = 0; d < 8; ++d) s += wih0r[g][d] * xv[d];
            g4[g] = s;
        }
        c0r = sigm(g4[1]) * c0r + sigm(g4[0]) * ftanh(g4[2]);
        float hn = sigm(g4[3]) * ftanh(c0r);
        ((unsigned short*)hstage)[bl * 8 + u] = f2bf(hn);
        __syncthreads();
        if (tid < 32) {
            int b = bg * 32 + tid;
            int chunk = ((b >> 4) * KS0 + (rb >> 2)) * 64 + ((b & 15) | ((rb & 3) << 4));
            cstore8((ull*)Hw + chunk * 2,     hstage[tid][0]);
            cstore8((ull*)Hw + chunk * 2 + 1, hstage[tid][1]);
        }
    };

    // ---- preamble: P1(0) ----
    loadP1(0);
    runP1(0);
    gbar(dom, rb, ++ep);

    for (int t = 0; t < NSTEP; ++t) {
        const int par = t & 1;
        unsigned short* H0w = par ? H0b : H0a;
        unsigned short* H1w = par ? H1b : H1a;
        const unsigned short* H1r = par ? H1a : H1b;

        // ================= P2 : layer 1 (K = 2048 = [h0(t) | h1(t-1)]) =======
        {
            f32x4 acc[2][2];
            #pragma unroll
            for (int m = 0; m < 2; ++m)
                #pragma unroll
                for (int ot = 0; ot < 2; ++ot) acc[m][ot] = (f32x4){0.f, 0.f, 0.f, 0.f};
            const unsigned short* src = (wv < 2) ? H0w : H1r;
            const int kb = (wv & 1) * 16;
            #pragma unroll
            for (int kk = 0; kk < 16; ++kk) {
                short8 a0 = cload(src + (((bg * 2 + 0) * KS0 + kb + kk) * 64 + lane) * 8);
                short8 a1 = cload(src + (((bg * 2 + 1) * KS0 + kb + kk) * 64 + lane) * 8);
                #pragma unroll
                for (int ot = 0; ot < 2; ++ot) {
                    acc[0][ot] = __builtin_amdgcn_mfma_f32_16x16x32_bf16(a0, Wr1[ot][kk], acc[0][ot], 0, 0, 0);
                    acc[1][ot] = __builtin_amdgcn_mfma_f32_16x16x32_bf16(a1, Wr1[ot][kk], acc[1][ot], 0, 0, 0);
                }
            }
            #pragma unroll
            for (int m = 0; m < 2; ++m)
                #pragma unroll
                for (int ot = 0; ot < 2; ++ot) {
                    int base = ((wv * 2 + m) * 2 + ot) * 272 + (lane & 15) * 17 + (lane >> 4) * 4;
                    #pragma unroll
                    for (int r = 0; r < 4; ++r) red[base + r] = acc[m][ot][r];
                }
            __syncthreads();
            float g4[4];
            #pragma unroll
            for (int g = 0; g < 4; ++g) {
                int rr = u * 4 + g, ot = rr >> 4, rr16 = rr & 15;
                float s = b1r[g];
                #pragma unroll
                for (int w2 = 0; w2 < 4; ++w2)
                    s += red[((w2 * 2 + mtl) * 2 + ot) * 272 + rr16 * 17 + m16];
                g4[g] = s;
            }
            c1r = sigm(g4[1]) * c1r + sigm(g4[0]) * ftanh(g4[2]);
            float hn = sigm(g4[3]) * ftanh(c1r);
            ((unsigned short*)hstage)[bl * 8 + u] = f2bf(hn);
            __syncthreads();
            if (tid < 32) {
                int b = bg * 32 + tid;
                int chunk = ((b >> 4) * KS0 + (rb >> 2)) * 64 + ((b & 15) | ((rb & 3) << 4));
                cstore8((ull*)H1w + chunk * 2,     hstage[tid][0]);
                cstore8((ull*)H1w + chunk * 2 + 1, hstage[tid][1]);
            }
        }
        gbar(dom, rb, ++ep);

        // ============ merged window: prefetch P1(t+1), P3(t), run P1(t+1) ====
        if (t < NSTEP - 1) loadP1(t + 1);   // overlaps P3's load latency

        {   // P3 : layer 2 (replicated per block)
            f32x4 acc[2][2];
            #pragma unroll
            for (int m = 0; m < 2; ++m)
                #pragma unroll
                for (int ot = 0; ot < 2; ++ot) acc[m][ot] = (f32x4){0.f, 0.f, 0.f, 0.f};
            #pragma unroll
            for (int kk = 0; kk < 8; ++kk) {
                short8 a0 = cload(H1w + (((bg * 2 + 0) * KS0 + 8 * wv + kk) * 64 + lane) * 8);
                short8 a1 = cload(H1w + (((bg * 2 + 1) * KS0 + 8 * wv + kk) * 64 + lane) * 8);
                #pragma unroll
                for (int ot = 0; ot < 2; ++ot) {
                    acc[0][ot] = __builtin_amdgcn_mfma_f32_16x16x32_bf16(a0, Wr2[ot][kk], acc[0][ot], 0, 0, 0);
                    acc[1][ot] = __builtin_amdgcn_mfma_f32_16x16x32_bf16(a1, Wr2[ot][kk], acc[1][ot], 0, 0, 0);
                }
            }
            #pragma unroll
            for (int m = 0; m < 2; ++m)
                #pragma unroll
                for (int ot = 0; ot < 2; ++ot) {
                    int base = ((wv * 2 + m) * 2 + ot) * 272 + (lane & 15) * 17 + (lane >> 4) * 4;
                    #pragma unroll
                    for (int r = 0; r < 4; ++r) red[base + r] = acc[m][ot][r];
                }
            __syncthreads();
            float xo[8];
            #pragma unroll
            for (int d = 0; d < 8; ++d) xo[d] = h2x[bl * 9 + d];
            float g4[4];
            #pragma unroll
            for (int g = 0; g < 4; ++g) {
                int rr = u * 4 + g, ot = rr >> 4, rr16 = rr & 15;
                float s = b2r[g];
                #pragma unroll
                for (int w2 = 0; w2 < 4; ++w2)
                    s += red[((w2 * 2 + mtl) * 2 + ot) * 272 + rr16 * 17 + m16];
                #pragma unroll
                for (int d = 0; d < 8; ++d) s += whh2r[g][d] * xo[d];
                g4[g] = s;
            }
            float cn = sigm(g4[1]) * c2r + sigm(g4[0]) * ftanh(g4[2]);
            c2r = cn;
            float hn = sigm(g4[3]) * ftanh(cn);
            __syncthreads();               // old-h2x reads done before overwrite
            h2x[bl * 9 + u] = hn;
            if (rb == 0 && t >= ENC - 1)
                pred[((bg * 32 + bl) * HOR + (t - (ENC - 1))) * DD + u] = hn;
        }

        if (t < NSTEP - 1) {
            runP1(t + 1);                  // red reuse safe: P3's 2nd sync passed
            gbar(dom, rb, ++ep);
        }
    }
}

// ---------------- host ----------------

extern "C" void kernel_launch(void* const* d_in, const int* in_sizes, int n_in,
                              void* d_out, int out_size, void* d_ws, size_t ws_size,
                              hipStream_t stream)
{
    const float* inp  = (const float*)d_in[0];
    const float* wih0 = (const float*)d_in[1];
    const float* whh0 = (const float*)d_in[2];
    const float* b0v  = (const float*)d_in[3];
    const float* wih1 = (const float*)d_in[4];
    const float* whh1 = (const float*)d_in[5];
    const float* b1v  = (const float*)d_in[6];
    const float* wih2 = (const float*)d_in[7];
    const float* whh2 = (const float*)d_in[8];
    const float* b2v  = (const float*)d_in[9];
    float* out = (float*)d_out;   // pred[172032] | y[172032] | loss[8]

    char* base = (char*)d_ws;
    size_t off = 0;
    auto carve = [&](size_t bytes) -> void* {
        void* p = base + off;
        off += (bytes + 255) & ~((size_t)255);
        return p;
    };
    unsigned short* Wp0 = (unsigned short*)carve((size_t)128 * 2 * KS0 * 64 * 8 * 2);
    unsigned short* Wp1 = (unsigned short*)carve((size_t)128 * 2 * KS1 * 64 * 8 * 2);
    unsigned short* Wp2 = (unsigned short*)carve((size_t)2 * KS0 * 64 * 8 * 2);
    size_t state_off = off;
    unsigned short* H0a = (unsigned short*)carve(B64 * H * 2);
    unsigned short* H0b = (unsigned short*)carve(B64 * H * 2);
    unsigned short* H1a = (unsigned short*)carve(B64 * H * 2);
    unsigned short* H1b = (unsigned short*)carve(B64 * H * 2);
    unsigned* bar = (unsigned*)carve(2 * 8192 * 4);   // 2 domains x 32KB
    size_t state_bytes = off - state_off;
    if (off > ws_size) return;

    zero_k<<<64, 256, 0, stream>>>((unsigned int*)(base + state_off), (int)(state_bytes / 4));
    pack0_k<<<2048, 256, 0, stream>>>(whh0, Wp0);
    pack1_k<<<4096, 256, 0, stream>>>(wih1, whh1, Wp1);
    pack2_k<<<32, 256, 0, stream>>>(wih2, Wp2);
    copy_y_k<<<672, 256, 0, stream>>>(inp, out + 172032);

    persist_k<<<NBLK, 256, 0, stream>>>(Wp0, Wp1, Wp2, wih0, b0v, b1v, whh2, b2v,
                                        inp, H0a, H0b, H1a, H1b, bar, out);

    loss_k<<<1, 256, 0, stream>>>(out, out + 172032, out + 344064);
}